// Round 1
// baseline (28784.195 us; speedup 1.0000x reference)
//
#include <hip/hip_runtime.h>
#include <hip/hip_cooperative_groups.h>
#include <hip/hip_bf16.h>
#include <cstdint>
#include <cstddef>

namespace cg = cooperative_groups;

// ---------------------------------------------------------------------------
// CustomLSTM: 2-layer LSTM, SEQ=512, B=64, IN=HS=1024.
// Round 2: persistent cooperative kernel.
//   - ONE kernel for all 1024 layer-steps; layers pipelined as a wavefront
//     (layer1 step t-1 runs concurrently with layer0 step t). 513 grid syncs
//     replace 1024 kernel launches.
//   - 256 blocks x 512 threads = all 256 CUs (was 64). Each block owns 8
//     hidden units of one layer; cell state c lives in REGISTERS for the
//     whole sequence; weights stay L2-resident via the stable block->CU map.
//   - Same numerics as round 1: bf16 MFMA 16x16x32, fp32 accum, fp32 cell.
// ---------------------------------------------------------------------------

typedef __attribute__((ext_vector_type(8))) short short8;     // 8 x bf16
typedef __attribute__((ext_vector_type(4))) float floatx4;    // MFMA acc

#define SEQL  512
#define BATCH 64
#define HSZ   1024
#define STEP_ELEMS 65536     // 64*1024, one timestep's h/x slab

// ---- workspace layout (bytes) ---------------------------------------------
// Wfrag  : 2 layers * 4096 * 2048 bf16 (fragment-ordered)  = 33,554,432
// xbf    : 512*64*1024 bf16                                = 67,108,864
// out0   : 512*64*1024 bf16 (layer-0 h history = L1 input) = 67,108,864
// hping  : 2 * 65536 bf16 (layer-1 h ping-pong)            =    262,144
// hzero  : 65536 bf16                                      =    131,072
// bias   : 2 * 4096 fp32                                   =     32,768
// total ≈ 168.2 MB
#define OFF_WFRAG  ((size_t)0)
#define OFF_XBF    ((size_t)33554432)
#define OFF_OUT0   ((size_t)100663296)
#define OFF_HPING  ((size_t)167772160)
#define OFF_HZERO  ((size_t)168034304)
#define OFF_BIAS   ((size_t)168165376)

// ---------------------------------------------------------------------------
// prep_misc: zero hzero, fuse biases. 288 x 256.
// ---------------------------------------------------------------------------
__global__ __launch_bounds__(256) void prep_misc(
    const float* __restrict__ bih0, const float* __restrict__ bhh0,
    const float* __restrict__ bih1, const float* __restrict__ bhh1,
    __hip_bfloat16* __restrict__ hzero, float* __restrict__ bias)
{
    int idx = blockIdx.x * 256 + threadIdx.x;           // 0..73727
    if (idx < 65536) {
        hzero[idx] = __float2bfloat16(0.f);
    } else {
        int rr = idx - 65536;
        if (rr < 8192) {
            int l = rr >> 12;
            int n = rr & 4095;
            bias[l * 4096 + n] = l ? (bih1[n] + bhh1[n]) : (bih0[n] + bhh0[n]);
        }
    }
}

// ---------------------------------------------------------------------------
// prep_x: fp32 -> bf16 conversion of the input tensor. 32768 x 256, 4/thread.
// ---------------------------------------------------------------------------
__global__ __launch_bounds__(256) void prep_x(
    const float* __restrict__ x, __hip_bfloat16* __restrict__ xbf)
{
    size_t i = ((size_t)blockIdx.x * 256 + threadIdx.x) * 4;
    float4 v = *(const float4*)(x + i);
    alignas(8) __hip_bfloat16 t[4];
    t[0] = __float2bfloat16(v.x);
    t[1] = __float2bfloat16(v.y);
    t[2] = __float2bfloat16(v.z);
    t[3] = __float2bfloat16(v.w);
    *(uint64_t*)(xbf + i) = *(const uint64_t*)t;
}

// ---------------------------------------------------------------------------
// prep_w: fragment-ordered bf16 weights for the NEW decomposition.
// Block (layer, b in 0..127) owns 8 hidden units j0 = b*8, all 4 gates
// packed as 2 N-tiles of 16 cols: tile nt, col c: gate = nt*2 + (c>>3),
// unit = c&7. MFMA 16x16x32 B-frag: n = lane&15 (=c), k = kk*32+(lane>>4)*8+j.
// Storage idx = (((layer*128 + b)*64 + kk)*2 + nt)*64 + lane  (short8 units).
// 8192 x 256 = 2,097,152 threads, one 16-B fragment each.
// ---------------------------------------------------------------------------
__global__ __launch_bounds__(256) void prep_w(
    const float* __restrict__ U0, const float* __restrict__ V0,
    const float* __restrict__ U1, const float* __restrict__ V1,
    short8* __restrict__ Wf)
{
    int idx = blockIdx.x * 256 + threadIdx.x;   // 0..2,097,151
    int lane  = idx & 63;
    int nt    = (idx >> 6) & 1;
    int kk    = (idx >> 7) & 63;
    int b     = (idx >> 13) & 127;
    int layer = idx >> 20;

    const float* U = layer ? U1 : U0;
    const float* V = layer ? V1 : V0;
    int c    = lane & 15;
    int gate = nt * 2 + (c >> 3);
    int wrow = gate * 1024 + b * 8 + (c & 7);
    int k    = kk * 32 + ((lane >> 4) * 8);
    const float* src = (k < 1024) ? (U + (size_t)wrow * 1024 + k)
                                  : (V + (size_t)wrow * 1024 + (k - 1024));
    float4 v0 = *(const float4*)(src);
    float4 v1 = *(const float4*)(src + 4);
    alignas(16) __hip_bfloat16 t[8];
    t[0] = __float2bfloat16(v0.x); t[1] = __float2bfloat16(v0.y);
    t[2] = __float2bfloat16(v0.z); t[3] = __float2bfloat16(v0.w);
    t[4] = __float2bfloat16(v1.x); t[5] = __float2bfloat16(v1.y);
    t[6] = __float2bfloat16(v1.z); t[7] = __float2bfloat16(v1.w);
    Wf[idx] = *(const short8*)t;
}

// ---------------------------------------------------------------------------
// lstm_persist: the whole 2-layer sequence in one cooperative kernel.
// grid 256 x 512 threads (8 waves). blk>>7 = layer, blk&127 = unit group.
// Waves: mt = w&3 (16 batch rows), nt = w>>2 (gate-pair tile). Each wave
// accumulates ONE 16x16 C-tile over K=2048 (64 MFMAs per step).
// Iteration u: layer0 does t=u (u<512), layer1 does t=u-1 (u>=1); grid.sync.
// ---------------------------------------------------------------------------
__global__ __launch_bounds__(512) void lstm_persist(
    const __hip_bfloat16* __restrict__ xbf,    // [512][64][1024] bf16
    __hip_bfloat16* __restrict__ out0,         // [512][64][1024] bf16 (L0 h)
    const short8* __restrict__ Wf,             // fragment weights
    const float* __restrict__ bias,            // [2][4096] fused bias
    const __hip_bfloat16* __restrict__ hzero,  // [64][1024] zeros
    __hip_bfloat16* __restrict__ hping,        // [2][64][1024] L1 h ping-pong
    float* __restrict__ out1,                  // [512][64][1024] fp32
    float* __restrict__ hf,                    // [2][64][1024] fp32
    float* __restrict__ cf)                    // [2][64][1024] fp32
{
    __shared__ short Alds[64][264];            // 256-wide K chunk, +8 pad
    __shared__ float Glds[2][64][17];          // gate C-tiles, padded

    cg::grid_group grid = cg::this_grid();

    const int blk   = blockIdx.x;
    const int layer = blk >> 7;
    const int ug    = blk & 127;               // unit group: units ug*8..+7
    const int tid   = threadIdx.x;
    const int w     = tid >> 6;
    const int lane  = tid & 63;
    const int mt    = w & 3;
    const int nt    = w >> 2;                  // 0: gates{i,f}, 1: gates{g,o}
    const int arow  = mt * 16 + (lane & 15);
    const int acol  = (lane >> 4) * 8;
    const size_t wbase = (size_t)blk * 8192;   // short8 frags per block

    // cell-phase constants: thread owns (batch row crow, unit j)
    const int crow = tid >> 3;
    const int jj   = tid & 7;
    const int j    = ug * 8 + jj;
    const float bi  = bias[layer * 4096 + j];
    const float bff = bias[layer * 4096 + 1024 + j];
    const float bg  = bias[layer * 4096 + 2048 + j];
    const float bo  = bias[layer * 4096 + 3072 + j];
    float c_reg = 0.f;                         // cell state, resident 512 steps

    for (int u = 0; u <= SEQL; ++u) {
        const int t = layer ? (u - 1) : u;
        const bool active = layer ? (u >= 1) : (u < SEQL);
        if (active) {
            const __hip_bfloat16* xpart =
                layer ? (out0 + (size_t)t * STEP_ELEMS)
                      : (xbf + (size_t)t * STEP_ELEMS);
            const __hip_bfloat16* hprev =
                (t == 0) ? hzero
                         : (layer ? (hping + (size_t)((t - 1) & 1) * STEP_ELEMS)
                                  : (out0 + (size_t)(t - 1) * STEP_ELEMS));

            floatx4 acc = {0.f, 0.f, 0.f, 0.f};
            for (int kc = 0; kc < 8; ++kc) {
                __syncthreads();               // protect prior chunk's reads
                const __hip_bfloat16* src =
                    (kc < 4) ? (xpart + kc * 256) : (hprev + (kc - 4) * 256);
                #pragma unroll
                for (int u4 = 0; u4 < 4; ++u4) {
                    int e = tid + u4 * 512;    // 0..2047 16-B units
                    int row  = e >> 5;
                    int col8 = (e & 31) * 8;
                    float4 v = *(const float4*)(src + row * 1024 + col8);
                    *(float4*)&Alds[row][col8] = v;
                }
                __syncthreads();
                #pragma unroll
                for (int kl = 0; kl < 8; ++kl) {
                    int kk = kc * 8 + kl;
                    short8 a  = *(const short8*)&Alds[arow][kl * 32 + acol];
                    short8 bq = Wf[wbase + (size_t)(kk * 2 + nt) * 64 + lane];
                    acc = __builtin_amdgcn_mfma_f32_16x16x32_bf16(a, bq, acc,
                                                                  0, 0, 0);
                }
            }

            // stage C-tiles (col = lane&15, row = (lane>>4)*4 + r)
            {
                const int col = lane & 15;
                const int rq  = (lane >> 4) * 4;
                #pragma unroll
                for (int r = 0; r < 4; ++r)
                    Glds[nt][mt * 16 + rq + r][col] = acc[r];
            }
            __syncthreads();

            // fused LSTM cell: this thread's (crow, j)
            {
                float gi = Glds[0][crow][jj]     + bi;
                float gf = Glds[0][crow][8 + jj] + bff;
                float gg = Glds[1][crow][jj]     + bg;
                float go = Glds[1][crow][8 + jj] + bo;
                float iv = 1.f / (1.f + __expf(-gi));
                float fv = 1.f / (1.f + __expf(-gf));
                float gv = tanhf(gg);
                float ov = 1.f / (1.f + __expf(-go));
                float cn = fv * c_reg + iv * gv;
                float hn = ov * tanhf(cn);
                c_reg = cn;
                const int cidx = crow * 1024 + j;
                __hip_bfloat16* hout =
                    layer ? (hping + (size_t)(t & 1) * STEP_ELEMS)
                          : (out0 + (size_t)t * STEP_ELEMS);
                hout[cidx] = __float2bfloat16(hn);
                if (layer) out1[(size_t)t * STEP_ELEMS + cidx] = hn;
                if (t == SEQL - 1) {
                    hf[(size_t)layer * STEP_ELEMS + cidx] = hn;
                    cf[(size_t)layer * STEP_ELEMS + cidx] = cn;
                }
            }
        }
        grid.sync();
    }
}

// ---------------------------------------------------------------------------
extern "C" void kernel_launch(void* const* d_in, const int* in_sizes, int n_in,
                              void* d_out, int out_size, void* d_ws, size_t ws_size,
                              hipStream_t stream)
{
    const float* x    = (const float*)d_in[0];
    const float* U0   = (const float*)d_in[1];
    const float* V0   = (const float*)d_in[2];
    const float* bih0 = (const float*)d_in[3];
    const float* bhh0 = (const float*)d_in[4];
    const float* U1   = (const float*)d_in[5];
    const float* V1   = (const float*)d_in[6];
    const float* bih1 = (const float*)d_in[7];
    const float* bhh1 = (const float*)d_in[8];

    char* ws = (char*)d_ws;
    short8*         Wf    = (short8*)(ws + OFF_WFRAG);
    __hip_bfloat16* xbf   = (__hip_bfloat16*)(ws + OFF_XBF);
    __hip_bfloat16* out0  = (__hip_bfloat16*)(ws + OFF_OUT0);
    __hip_bfloat16* hping = (__hip_bfloat16*)(ws + OFF_HPING);
    __hip_bfloat16* hzero = (__hip_bfloat16*)(ws + OFF_HZERO);
    float*          bias  = (float*)(ws + OFF_BIAS);

    prep_misc<<<dim3(288), dim3(256), 0, stream>>>(bih0, bhh0, bih1, bhh1,
                                                   hzero, bias);
    prep_x<<<dim3(32768), dim3(256), 0, stream>>>(x, xbf);
    prep_w<<<dim3(8192), dim3(256), 0, stream>>>(U0, V0, U1, V1, Wf);

    float* out1 = (float*)d_out;               // [512][64][1024]
    float* hfp  = out1 + 33554432;             // [2][64][1024]
    float* cfp  = hfp + 131072;                // [2][64][1024]

    void* kargs[] = { (void*)&xbf, (void*)&out0, (void*)&Wf, (void*)&bias,
                      (void*)&hzero, (void*)&hping, (void*)&out1,
                      (void*)&hfp, (void*)&cfp };
    hipLaunchCooperativeKernel((void*)lstm_persist, dim3(256), dim3(512),
                               kargs, 0, stream);
}

// Round 2
// 7750.466 us; speedup vs baseline: 3.7139x; 3.7139x over previous
//
#include <hip/hip_runtime.h>
#include <hip/hip_bf16.h>
#include <cstdint>
#include <cstddef>

// ---------------------------------------------------------------------------
// CustomLSTM: 2-layer LSTM, SEQ=512, B=64, IN=HS=1024.
// Round 3: persistent kernel with MANUAL cross-XCD coherence.
//   - grid.sync (L2-invalidating, ~56us/iter in round 2) replaced by a
//     spread-counter MALL barrier + per-access coherent (sc0 sc1) loads/stores
//     for exactly the data that crosses XCDs (h slabs). Weights stay plain
//     cached -> per-XCD L2 remains weight-resident across all 512 steps.
//   - 256 blocks = 2 M-splits x 64 unit-groups x 2 layers. Siblings (same
//     unit-group, different M-split) differ by 64 in blockIdx => same XCD
//     under round-robin mapping => 4 MB weights/XCD = exact L2 fit.
//   - Cell state c in registers for the whole sequence. Numerics identical
//     to rounds 1/2 (bf16 MFMA 16x16x32, fp32 accumulate, fp32 cell).
// ---------------------------------------------------------------------------

typedef __attribute__((ext_vector_type(8))) short short8;     // 8 x bf16
typedef __attribute__((ext_vector_type(4))) float floatx4;    // MFMA acc
typedef __attribute__((ext_vector_type(4))) float f32x4;      // asm payload

#define SEQL  512
#define BATCH 64
#define HSZ   1024
#define STEP_ELEMS 65536     // 64*1024, one timestep's h/x slab

// ---- workspace layout (bytes) ---------------------------------------------
// Wfrag  : 2 layers * 4096 * 2048 bf16 (fragment-ordered)  = 33,554,432
// xbf    : 512*64*1024 bf16                                = 67,108,864
// out0   : 512*64*1024 bf16 (layer-0 h history = L1 input) = 67,108,864
// hping  : 2 * 65536 bf16 (layer-1 h ping-pong)            =    262,144
// hzero  : 65536 bf16                                      =    131,072
// bias   : 2 * 4096 fp32                                   =     32,768
// barcnt : 16 counters * 128 B                              =      2,048
#define OFF_WFRAG  ((size_t)0)
#define OFF_XBF    ((size_t)33554432)
#define OFF_OUT0   ((size_t)100663296)
#define OFF_HPING  ((size_t)167772160)
#define OFF_HZERO  ((size_t)168034304)
#define OFF_BIAS   ((size_t)168165376)
#define OFF_BAR    ((size_t)168198144)

// ---------------------------------------------------------------------------
// coherent (cross-XCD) access helpers: sc0 sc1 bypasses L1+L2, serves from
// the shared MALL/Infinity-Cache coherence point.
// ---------------------------------------------------------------------------
__device__ __forceinline__ void stage2_coh(const __hip_bfloat16* p0,
                                           const __hip_bfloat16* p1,
                                           f32x4& v0, f32x4& v1)
{
    asm volatile(
        "global_load_dwordx4 %0, %2, off sc0 sc1\n\t"
        "global_load_dwordx4 %1, %3, off sc0 sc1\n\t"
        "s_waitcnt vmcnt(0)"
        : "=&v"(v0), "=&v"(v1)
        : "v"(p0), "v"(p1)
        : "memory");
}

__device__ __forceinline__ unsigned ld_coh_u32(const unsigned* p)
{
    unsigned d;
    asm volatile("global_load_dword %0, %1, off sc0 sc1\n\t"
                 "s_waitcnt vmcnt(0)"
                 : "=v"(d) : "v"(p) : "memory");
    return d;
}

__device__ __forceinline__ void st_coh_u32(unsigned* p, unsigned v)
{
    asm volatile("global_store_dword %0, %1, off sc0 sc1"
                 :: "v"(p), "v"(v) : "memory");
}

// ---------------------------------------------------------------------------
// prep_misc: zero hzero + barrier counters, fuse biases. 291 x 256.
// ---------------------------------------------------------------------------
__global__ __launch_bounds__(256) void prep_misc(
    const float* __restrict__ bih0, const float* __restrict__ bhh0,
    const float* __restrict__ bih1, const float* __restrict__ bhh1,
    __hip_bfloat16* __restrict__ hzero, float* __restrict__ bias,
    unsigned* __restrict__ barcnt)
{
    int idx = blockIdx.x * 256 + threadIdx.x;
    if (idx < 65536) {
        hzero[idx] = __float2bfloat16(0.f);
    } else if (idx < 73728) {
        int rr = idx - 65536;
        int l = rr >> 12;
        int n = rr & 4095;
        bias[l * 4096 + n] = l ? (bih1[n] + bhh1[n]) : (bih0[n] + bhh0[n]);
    } else if (idx < 74240) {
        barcnt[idx - 73728] = 0u;
    }
}

// ---------------------------------------------------------------------------
// prep_x: fp32 -> bf16 conversion of the input tensor. 32768 x 256, 4/thread.
// ---------------------------------------------------------------------------
__global__ __launch_bounds__(256) void prep_x(
    const float* __restrict__ x, __hip_bfloat16* __restrict__ xbf)
{
    size_t i = ((size_t)blockIdx.x * 256 + threadIdx.x) * 4;
    float4 v = *(const float4*)(x + i);
    alignas(8) __hip_bfloat16 t[4];
    t[0] = __float2bfloat16(v.x);
    t[1] = __float2bfloat16(v.y);
    t[2] = __float2bfloat16(v.z);
    t[3] = __float2bfloat16(v.w);
    *(uint64_t*)(xbf + i) = *(const uint64_t*)t;
}

// ---------------------------------------------------------------------------
// prep_w: fragment-ordered bf16 weights.
// Unit-group g (0..63) owns hidden units g*16..+15; N-tile n = gate n (i,f,g,o).
// MFMA 16x16x32 B-frag: col c = lane&15, k = kk*32 + (lane>>4)*8 + j.
// W row = n*1024 + g*16 + c; k<1024 -> U, else V  (K = [x|h]).
// Storage idx = ((((layer*64+g)*64+kk)*4+n)*64+lane) == linear thread idx.
// ---------------------------------------------------------------------------
__global__ __launch_bounds__(256) void prep_w(
    const float* __restrict__ U0, const float* __restrict__ V0,
    const float* __restrict__ U1, const float* __restrict__ V1,
    short8* __restrict__ Wf)
{
    int idx = blockIdx.x * 256 + threadIdx.x;   // 0..2,097,151
    int lane  = idx & 63;
    int n     = (idx >> 6) & 3;
    int kk    = (idx >> 8) & 63;
    int g     = (idx >> 14) & 63;
    int layer = (idx >> 20) & 1;

    const float* U = layer ? U1 : U0;
    const float* V = layer ? V1 : V0;
    int c    = lane & 15;
    int wrow = n * 1024 + g * 16 + c;
    int k    = kk * 32 + ((lane >> 4) * 8);
    const float* src = (k < 1024) ? (U + (size_t)wrow * 1024 + k)
                                  : (V + (size_t)wrow * 1024 + (k - 1024));
    float4 v0 = *(const float4*)(src);
    float4 v1 = *(const float4*)(src + 4);
    alignas(16) __hip_bfloat16 t[8];
    t[0] = __float2bfloat16(v0.x); t[1] = __float2bfloat16(v0.y);
    t[2] = __float2bfloat16(v0.z); t[3] = __float2bfloat16(v0.w);
    t[4] = __float2bfloat16(v1.x); t[5] = __float2bfloat16(v1.y);
    t[6] = __float2bfloat16(v1.z); t[7] = __float2bfloat16(v1.w);
    Wf[idx] = *(const short8*)t;
}

// ---------------------------------------------------------------------------
// lstm_persist: whole 2-layer sequence, one cooperative kernel, custom barrier.
// blk = layer*128 + msplit*64 + g. Block covers batch rows msplit*32..+31,
// hidden units g*16..+15, all 4 gates. 8 waves: mt = w&1 (16 rows),
// nq = w>>1 (gate). Each wave: one 16x16 C-tile over K=2048 (64 MFMAs/step).
// Iteration u: layer0 does t=u (u<512), layer1 does t=u-1 (u>=1); barrier.
// ---------------------------------------------------------------------------
__global__ __launch_bounds__(512) void lstm_persist(
    const __hip_bfloat16* __restrict__ xbf,    // [512][64][1024] bf16
    __hip_bfloat16* __restrict__ out0,         // [512][64][1024] bf16 (L0 h)
    const short8* __restrict__ Wf,             // fragment weights
    const float* __restrict__ bias,            // [2][4096] fused bias
    const __hip_bfloat16* __restrict__ hzero,  // [64][1024] zeros
    __hip_bfloat16* __restrict__ hping,        // [2][64][1024] L1 h ping-pong
    float* __restrict__ out1,                  // [512][64][1024] fp32
    float* __restrict__ hf,                    // [2][64][1024] fp32
    float* __restrict__ cf,                    // [2][64][1024] fp32
    unsigned* __restrict__ barcnt)             // 16 counters, 128B stride
{
    __shared__ short Alds[32][264];            // 32 rows x 256-K chunk, +8 pad
    __shared__ float Glds[4][32][17];          // gate C-tiles, padded

    const int blk   = blockIdx.x;
    const int layer = blk >> 7;
    const int ms    = (blk >> 6) & 1;          // M-split
    const int g     = blk & 63;                // unit group (16 units)
    const int tid   = threadIdx.x;
    const int lane  = tid & 63;
    const int w     = tid >> 6;
    const int mt    = w & 1;                   // M-tile within the 32 rows
    const int nq    = w >> 1;                  // gate 0..3 (i,f,g,o)
    const int rs    = ms * 32;                 // batch-row start
    const int arow  = mt * 16 + (lane & 15);
    const int acol  = (lane >> 4) * 8;
    const size_t wbase = (size_t)(layer * 64 + g) * 16384;  // short8 frags

    // staging coords: thread stages rows sr0 and sr0+16, 16B each
    const int sr0 = tid >> 5;                  // 0..15
    const int sc0 = (tid & 31) * 8;            // col in bf16 elems

    // cell-phase constants: thread owns (batch row grow, unit j)
    const int crow = tid >> 4;                 // 0..31 local row
    const int cc   = tid & 15;
    const int grow = rs + crow;
    const int j    = g * 16 + cc;
    const float bi  = bias[layer * 4096 + j];
    const float bfv = bias[layer * 4096 + 1024 + j];
    const float bg  = bias[layer * 4096 + 2048 + j];
    const float bo  = bias[layer * 4096 + 3072 + j];
    float c_reg = 0.f;                         // cell state, resident 512 steps

    for (int u = 0; u <= SEQL; ++u) {
        const int t = layer ? (u - 1) : u;
        const bool active = layer ? (u >= 1) : (u < SEQL);
        if (active) {
            const __hip_bfloat16* xpart =
                layer ? (out0 + (size_t)t * STEP_ELEMS)
                      : (xbf + (size_t)t * STEP_ELEMS);
            const __hip_bfloat16* hprev =
                (t == 0) ? hzero
                         : (layer ? (hping + (size_t)((t - 1) & 1) * STEP_ELEMS)
                                  : (out0 + (size_t)(t - 1) * STEP_ELEMS));

            floatx4 acc = {0.f, 0.f, 0.f, 0.f};
            for (int kc = 0; kc < 8; ++kc) {
                __syncthreads();               // protect prior chunk's reads
                const __hip_bfloat16* src =
                    (kc < 4) ? (xpart + (size_t)(rs + sr0) * 1024 + kc * 256 + sc0)
                             : (hprev + (size_t)(rs + sr0) * 1024 + (kc - 4) * 256 + sc0);
                f32x4 v0, v1;
                stage2_coh(src, src + 16 * 1024, v0, v1);
                *(f32x4*)&Alds[sr0][sc0]      = v0;
                *(f32x4*)&Alds[sr0 + 16][sc0] = v1;
                __syncthreads();
                #pragma unroll
                for (int kl = 0; kl < 8; ++kl) {
                    int kk = kc * 8 + kl;
                    short8 a = *(const short8*)&Alds[arow][kl * 32 + acol];
                    short8 b = Wf[wbase + (size_t)(kk * 4 + nq) * 64 + lane];
                    acc = __builtin_amdgcn_mfma_f32_16x16x32_bf16(a, b, acc,
                                                                  0, 0, 0);
                }
            }

            // stage C-tile (col = lane&15, row = (lane>>4)*4 + r)
            {
                const int col = lane & 15;
                const int rq  = (lane >> 4) * 4;
                #pragma unroll
                for (int r = 0; r < 4; ++r)
                    Glds[nq][mt * 16 + rq + r][col] = acc[r];
            }
            __syncthreads();

            // fused LSTM cell: this thread's (grow, j)
            {
                float gi = Glds[0][crow][cc] + bi;
                float gf = Glds[1][crow][cc] + bfv;
                float gg = Glds[2][crow][cc] + bg;
                float go = Glds[3][crow][cc] + bo;
                float iv = 1.f / (1.f + __expf(-gi));
                float fv = 1.f / (1.f + __expf(-gf));
                float gv = tanhf(gg);
                float ov = 1.f / (1.f + __expf(-go));
                float cn = fv * c_reg + iv * gv;
                float hn = ov * tanhf(cn);
                c_reg = cn;

                __hip_bfloat16 hb = __float2bfloat16(hn);
                unsigned hu = *(const unsigned short*)&hb;
                unsigned other = (unsigned)__shfl_xor((int)hu, 1);
                if ((cc & 1) == 0) {
                    unsigned pack = hu | (other << 16);
                    __hip_bfloat16* hout =
                        layer ? (hping + (size_t)(t & 1) * STEP_ELEMS)
                              : (out0 + (size_t)t * STEP_ELEMS);
                    st_coh_u32((unsigned*)(hout + (size_t)grow * 1024 + j), pack);
                }
                if (layer)
                    __builtin_nontemporal_store(
                        hn, out1 + (size_t)t * STEP_ELEMS + grow * 1024 + j);
                if (t == SEQL - 1) {
                    __builtin_nontemporal_store(
                        hn, hf + (size_t)layer * STEP_ELEMS + grow * 1024 + j);
                    __builtin_nontemporal_store(
                        cn, cf + (size_t)layer * STEP_ELEMS + grow * 1024 + j);
                }
            }
        }

        // ---- MALL barrier (no cache invalidation) -------------------------
        if (u < SEQL) {
            // drain: compiler emits s_waitcnt vmcnt(0) before s_barrier for
            // EVERY wave => all write-through h-stores are globally visible.
            __syncthreads();
            if (tid == 0)
                __hip_atomic_fetch_add(&barcnt[(blk & 15) * 32], 1u,
                                       __ATOMIC_RELAXED,
                                       __HIP_MEMORY_SCOPE_AGENT);
            if (tid < 64) {
                const unsigned tgt = (unsigned)(u + 1) * 16u;  // 16 blocks/counter
                const bool mine = (tid < 16);
                for (;;) {
                    unsigned v = tgt;
                    if (mine) v = ld_coh_u32(&barcnt[tid * 32]);
                    if (__all((int)(v >= tgt))) break;
                    __builtin_amdgcn_s_sleep(2);
                }
            }
            __syncthreads();
        }
    }
}

// ---------------------------------------------------------------------------
extern "C" void kernel_launch(void* const* d_in, const int* in_sizes, int n_in,
                              void* d_out, int out_size, void* d_ws, size_t ws_size,
                              hipStream_t stream)
{
    const float* x    = (const float*)d_in[0];
    const float* U0   = (const float*)d_in[1];
    const float* V0   = (const float*)d_in[2];
    const float* bih0 = (const float*)d_in[3];
    const float* bhh0 = (const float*)d_in[4];
    const float* U1   = (const float*)d_in[5];
    const float* V1   = (const float*)d_in[6];
    const float* bih1 = (const float*)d_in[7];
    const float* bhh1 = (const float*)d_in[8];

    char* ws = (char*)d_ws;
    short8*         Wf    = (short8*)(ws + OFF_WFRAG);
    __hip_bfloat16* xbf   = (__hip_bfloat16*)(ws + OFF_XBF);
    __hip_bfloat16* out0  = (__hip_bfloat16*)(ws + OFF_OUT0);
    __hip_bfloat16* hping = (__hip_bfloat16*)(ws + OFF_HPING);
    __hip_bfloat16* hzero = (__hip_bfloat16*)(ws + OFF_HZERO);
    float*          bias  = (float*)(ws + OFF_BIAS);
    unsigned*       barc  = (unsigned*)(ws + OFF_BAR);

    prep_misc<<<dim3(291), dim3(256), 0, stream>>>(bih0, bhh0, bih1, bhh1,
                                                   hzero, bias, barc);
    prep_x<<<dim3(32768), dim3(256), 0, stream>>>(x, xbf);
    prep_w<<<dim3(8192), dim3(256), 0, stream>>>(U0, V0, U1, V1, Wf);

    float* out1 = (float*)d_out;               // [512][64][1024]
    float* hfp  = out1 + 33554432;             // [2][64][1024]
    float* cfp  = hfp + 131072;                // [2][64][1024]

    void* kargs[] = { (void*)&xbf, (void*)&out0, (void*)&Wf, (void*)&bias,
                      (void*)&hzero, (void*)&hping, (void*)&out1,
                      (void*)&hfp, (void*)&cfp, (void*)&barc };
    hipLaunchCooperativeKernel((void*)lstm_persist, dim3(256), dim3(512),
                               kargs, 0, stream);
}

// Round 3
// 6456.224 us; speedup vs baseline: 4.4584x; 1.2005x over previous
//
#include <hip/hip_runtime.h>
#include <hip/hip_bf16.h>
#include <cstdint>
#include <cstddef>

// ---------------------------------------------------------------------------
// CustomLSTM: 2-layer LSTM, SEQ=512, B=64, IN=HS=1024.
// Round 4: register-resident GEMM.
//   - Weights live in VGPRs for the whole sequence (K-split across waves:
//     wave w owns kk=w*8..w*8+7 -> 16 frags = 64 VGPRs). Zero per-step
//     weight traffic (round 3 re-fetched 16.9 MB/step from beyond L2).
//   - No A-LDS: each lane loads its 32 MFMA A-fragments straight to
//     registers; ONE vmcnt(0) drain per step (was 8 serialized MALL RTs);
//     64 back-to-back MFMAs. LDS only for the 8-way K-partial reduction
//     (2-way conflicts max; round 3 had 2.85e8 conflicts).
//   - 256 blocks = 2 layers x 128 unit-groups (8 units x 4 gates = 32 cols).
//     Coherence: h slabs + L1 input via sc0 sc1 (MALL); L0 x plain cached.
//     Spread-counter MALL barrier (proven in round 3).
// ---------------------------------------------------------------------------

typedef __attribute__((ext_vector_type(8))) short short8;     // 8 x bf16
typedef __attribute__((ext_vector_type(4))) float floatx4;    // MFMA acc

#define SEQL  512
#define BATCH 64
#define HSZ   1024
#define STEP_ELEMS 65536     // 64*1024, one timestep's h/x slab

// ---- workspace layout (bytes) ---------------------------------------------
#define OFF_WFRAG  ((size_t)0)            // 33,554,432
#define OFF_XBF    ((size_t)33554432)     // 67,108,864
#define OFF_OUT0   ((size_t)100663296)    // 67,108,864
#define OFF_HPING  ((size_t)167772160)    //    262,144
#define OFF_HZERO  ((size_t)168034304)    //    131,072
#define OFF_BIAS   ((size_t)168165376)    //     32,768
#define OFF_BAR    ((size_t)168198144)    //      2,048

// ---------------------------------------------------------------------------
// coherent (cross-XCD) access helpers: sc0 sc1 -> MALL coherence point.
// ---------------------------------------------------------------------------
__device__ __forceinline__ short8 ld16_coh(const __hip_bfloat16* p)
{
    short8 d;
    asm volatile("global_load_dwordx4 %0, %1, off sc0 sc1"
                 : "=v"(d) : "v"(p) : "memory");
    return d;
}

__device__ __forceinline__ unsigned ld_coh_u32(const unsigned* p)
{
    unsigned d;
    asm volatile("global_load_dword %0, %1, off sc0 sc1\n\t"
                 "s_waitcnt vmcnt(0)"
                 : "=v"(d) : "v"(p) : "memory");
    return d;
}

__device__ __forceinline__ void st_coh_u32(unsigned* p, unsigned v)
{
    asm volatile("global_store_dword %0, %1, off sc0 sc1"
                 :: "v"(p), "v"(v) : "memory");
}

// ---------------------------------------------------------------------------
// prep_misc: zero hzero + barrier counters, fuse biases. 291 x 256.
// ---------------------------------------------------------------------------
__global__ __launch_bounds__(256) void prep_misc(
    const float* __restrict__ bih0, const float* __restrict__ bhh0,
    const float* __restrict__ bih1, const float* __restrict__ bhh1,
    __hip_bfloat16* __restrict__ hzero, float* __restrict__ bias,
    unsigned* __restrict__ barcnt)
{
    int idx = blockIdx.x * 256 + threadIdx.x;
    if (idx < 65536) {
        hzero[idx] = __float2bfloat16(0.f);
    } else if (idx < 73728) {
        int rr = idx - 65536;
        int l = rr >> 12;
        int n = rr & 4095;
        bias[l * 4096 + n] = l ? (bih1[n] + bhh1[n]) : (bih0[n] + bhh0[n]);
    } else if (idx < 74240) {
        barcnt[idx - 73728] = 0u;
    }
}

// ---------------------------------------------------------------------------
// prep_x: fp32 -> bf16 conversion of the input tensor. 32768 x 256, 4/thread.
// ---------------------------------------------------------------------------
__global__ __launch_bounds__(256) void prep_x(
    const float* __restrict__ x, __hip_bfloat16* __restrict__ xbf)
{
    size_t i = ((size_t)blockIdx.x * 256 + threadIdx.x) * 4;
    float4 v = *(const float4*)(x + i);
    alignas(8) __hip_bfloat16 t[4];
    t[0] = __float2bfloat16(v.x);
    t[1] = __float2bfloat16(v.y);
    t[2] = __float2bfloat16(v.z);
    t[3] = __float2bfloat16(v.w);
    *(uint64_t*)(xbf + i) = *(const uint64_t*)t;
}

// ---------------------------------------------------------------------------
// prep_w: fragment-ordered bf16 weights for the K-split decomposition.
// Block (layer, g 0..127) owns units g*8..+7, all 4 gates (32 N-cols:
// c = g4*8 + u, N-tile nt = c>>4). Wave w owns kk = w*8+kkl.
// B-frag (16x16x32): within-tile col = lane&15, k = kk*32 + (lane>>4)*8 + j.
// W row = g4*1024 + g*8 + u;  k<1024 -> U, else V  (K = [x|h]).
// Storage idx = ((((layer*128+g)*8 + w)*16 + nt*8 + kkl)*64 + lane) == idx.
// ---------------------------------------------------------------------------
__global__ __launch_bounds__(256) void prep_w(
    const float* __restrict__ U0, const float* __restrict__ V0,
    const float* __restrict__ U1, const float* __restrict__ V1,
    short8* __restrict__ Wf)
{
    int idx = blockIdx.x * 256 + threadIdx.x;   // 0..2,097,151
    int lane  = idx & 63;
    int f     = (idx >> 6) & 15;                // nt*8 + kkl
    int wv    = (idx >> 10) & 7;
    int g     = (idx >> 13) & 127;
    int layer = (idx >> 20) & 1;
    int kkl = f & 7;
    int nt  = f >> 3;
    int kk  = wv * 8 + kkl;
    int c   = nt * 16 + (lane & 15);            // 0..31
    int g4  = c >> 3;
    int uu  = c & 7;
    int wrow = g4 * 1024 + g * 8 + uu;
    int k    = kk * 32 + ((lane >> 4) * 8);
    const float* U = layer ? U1 : U0;
    const float* V = layer ? V1 : V0;
    const float* src = (k < 1024) ? (U + (size_t)wrow * 1024 + k)
                                  : (V + (size_t)wrow * 1024 + (k - 1024));
    float4 v0 = *(const float4*)(src);
    float4 v1 = *(const float4*)(src + 4);
    alignas(16) __hip_bfloat16 t[8];
    t[0] = __float2bfloat16(v0.x); t[1] = __float2bfloat16(v0.y);
    t[2] = __float2bfloat16(v0.z); t[3] = __float2bfloat16(v0.w);
    t[4] = __float2bfloat16(v1.x); t[5] = __float2bfloat16(v1.y);
    t[6] = __float2bfloat16(v1.z); t[7] = __float2bfloat16(v1.w);
    Wf[idx] = *(const short8*)t;
}

// ---------------------------------------------------------------------------
// lstm_persist: whole 2-layer sequence, one launch, register-resident weights.
// blk = layer*128 + g. 8 waves: wave w owns K-slice kk = w*8..w*8+7
// (waves 0-3: x-part of K, waves 4-7: h-part). Each wave computes partial
// C[64 rows x 32 cols] over its K-slice: 4 mt x 2 nt x 8 kk = 64 MFMAs.
// Partials reduced 8-way in LDS, fused with the LSTM cell (1 cell/thread).
// ---------------------------------------------------------------------------
__global__ __launch_bounds__(512, 2) void lstm_persist(
    const __hip_bfloat16* __restrict__ xbf,    // [512][64][1024] bf16
    __hip_bfloat16* __restrict__ out0,         // [512][64][1024] bf16 (L0 h)
    const short8* __restrict__ Wf,             // fragment weights
    const float* __restrict__ bias,            // [2][4096] fused bias
    const __hip_bfloat16* __restrict__ hzero,  // [64][1024] zeros
    __hip_bfloat16* __restrict__ hping,        // [2][64][1024] L1 h ping-pong
    float* __restrict__ out1,                  // [512][64][1024] fp32
    float* __restrict__ hf,                    // [2][64][1024] fp32
    float* __restrict__ cf,                    // [2][64][1024] fp32
    unsigned* __restrict__ barcnt)             // 16 counters, 128B stride
{
    __shared__ float Glds[8][64][36];          // K-partials, pad 36 (2-way max)

    const int blk   = blockIdx.x;
    const int layer = blk >> 7;
    const int g     = blk & 127;               // unit group (8 units)
    const int tid   = threadIdx.x;
    const int lane  = tid & 63;
    const int w     = tid >> 6;
    const int xw    = (w < 4) ? 1 : 0;         // wave reads x-part of K?
    const int colbase = (w & 3) * 256 + ((lane >> 4) * 8);
    const int arow    = lane & 15;

    // ---- weight preload: 16 frags = 64 VGPRs, resident for 512 steps ------
    short8 wf[2][8];
    const size_t wbase = (((size_t)layer * 128 + g) * 8 + w) * 1024;
    #pragma unroll
    for (int nt = 0; nt < 2; ++nt)
        #pragma unroll
        for (int kkl = 0; kkl < 8; ++kkl)
            wf[nt][kkl] = Wf[wbase + (size_t)((nt * 8 + kkl) * 64 + lane)];

    // ---- cell-phase constants: thread owns (row cr, unit cu) --------------
    const int cr = tid >> 3;                   // 0..63 batch row
    const int cu = tid & 7;                    // 0..7 unit within group
    const int j  = g * 8 + cu;                 // global hidden unit
    const float bi  = bias[layer * 4096 + j];
    const float bfv = bias[layer * 4096 + 1024 + j];
    const float bg  = bias[layer * 4096 + 2048 + j];
    const float bo  = bias[layer * 4096 + 3072 + j];
    float c_reg = 0.f;                         // cell state, 512 steps

    for (int u = 0; u <= SEQL; ++u) {
        const int t = layer ? (u - 1) : u;
        const bool active = layer ? (u >= 1) : (u < SEQL);
        if (active) {
            const __hip_bfloat16* xpart =
                layer ? (out0 + (size_t)t * STEP_ELEMS)
                      : (xbf + (size_t)t * STEP_ELEMS);
            const __hip_bfloat16* hprev =
                (t == 0) ? hzero
                         : (layer ? (hping + (size_t)((t - 1) & 1) * STEP_ELEMS)
                                  : (out0 + (size_t)(t - 1) * STEP_ELEMS));
            const __hip_bfloat16* abase =
                (xw ? xpart : hprev) + (size_t)arow * 1024 + colbase;

            // ---- A-fragments straight to registers ------------------------
            short8 a[4][8];
            if (!layer && xw) {
                // L0 x-part: static data -> plain cached loads
                #pragma unroll
                for (int mt = 0; mt < 4; ++mt)
                    #pragma unroll
                    for (int kkl = 0; kkl < 8; ++kkl)
                        a[mt][kkl] =
                            *(const short8*)(abase + mt * 16384 + kkl * 32);
            } else {
                // cross-XCD data: coherent loads, all 32 in flight, 1 drain
                #pragma unroll
                for (int mt = 0; mt < 4; ++mt)
                    #pragma unroll
                    for (int kkl = 0; kkl < 8; ++kkl)
                        a[mt][kkl] = ld16_coh(abase + mt * 16384 + kkl * 32);
                asm volatile("s_waitcnt vmcnt(0)" ::: "memory");
                __builtin_amdgcn_sched_barrier(0);
            }

            // ---- 64 register-only MFMAs -----------------------------------
            floatx4 acc[4][2];
            #pragma unroll
            for (int mt = 0; mt < 4; ++mt)
                #pragma unroll
                for (int nt = 0; nt < 2; ++nt)
                    acc[mt][nt] = (floatx4){0.f, 0.f, 0.f, 0.f};
            #pragma unroll
            for (int kkl = 0; kkl < 8; ++kkl)
                #pragma unroll
                for (int mt = 0; mt < 4; ++mt)
                    #pragma unroll
                    for (int nt = 0; nt < 2; ++nt)
                        acc[mt][nt] = __builtin_amdgcn_mfma_f32_16x16x32_bf16(
                            a[mt][kkl], wf[nt][kkl], acc[mt][nt], 0, 0, 0);

            // ---- K-partials to LDS (C: col = lane&15, row = (lane>>4)*4+r)
            {
                const int rq = (lane >> 4) * 4;
                const int cc = lane & 15;
                #pragma unroll
                for (int mt = 0; mt < 4; ++mt)
                    #pragma unroll
                    for (int nt = 0; nt < 2; ++nt)
                        #pragma unroll
                        for (int r = 0; r < 4; ++r)
                            Glds[w][mt * 16 + rq + r][nt * 16 + cc] =
                                acc[mt][nt][r];
            }
            __syncthreads();

            // ---- 8-way reduce + fused LSTM cell ---------------------------
            {
                float v0 = 0.f, v1 = 0.f, v2 = 0.f, v3 = 0.f;
                #pragma unroll
                for (int ww = 0; ww < 8; ++ww) {
                    v0 += Glds[ww][cr][cu];          // gate i  (c = 0*8+u)
                    v1 += Glds[ww][cr][8 + cu];      // gate f
                    v2 += Glds[ww][cr][16 + cu];     // gate g
                    v3 += Glds[ww][cr][24 + cu];     // gate o
                }
                float iv = 1.f / (1.f + __expf(-(v0 + bi)));
                float fv = 1.f / (1.f + __expf(-(v1 + bfv)));
                float gv = tanhf(v2 + bg);
                float ov = 1.f / (1.f + __expf(-(v3 + bo)));
                float cn = fv * c_reg + iv * gv;
                float hn = ov * tanhf(cn);
                c_reg = cn;

                __hip_bfloat16 hb = __float2bfloat16(hn);
                unsigned hu = *(const unsigned short*)&hb;
                unsigned other = (unsigned)__shfl_xor((int)hu, 1);
                if (!(cu & 1)) {
                    unsigned pack = hu | (other << 16);
                    __hip_bfloat16* hout =
                        layer ? (hping + (size_t)(t & 1) * STEP_ELEMS)
                              : (out0 + (size_t)t * STEP_ELEMS);
                    st_coh_u32((unsigned*)(hout + (size_t)cr * 1024 + j), pack);
                }
                if (layer)
                    __builtin_nontemporal_store(
                        hn, out1 + (size_t)t * STEP_ELEMS + cr * 1024 + j);
                if (t == SEQL - 1) {
                    __builtin_nontemporal_store(
                        hn, hf + (size_t)layer * STEP_ELEMS + cr * 1024 + j);
                    __builtin_nontemporal_store(
                        cn, cf + (size_t)layer * STEP_ELEMS + cr * 1024 + j);
                }
            }
        }

        // ---- MALL barrier (no cache invalidation) -------------------------
        if (u < SEQL) {
            asm volatile("s_waitcnt vmcnt(0)" ::: "memory");  // drain h-stores
            __syncthreads();
            if (tid == 0)
                __hip_atomic_fetch_add(&barcnt[(blk & 15) * 32], 1u,
                                       __ATOMIC_RELAXED,
                                       __HIP_MEMORY_SCOPE_AGENT);
            if (tid < 64) {
                const unsigned tgt = (unsigned)(u + 1) * 16u;
                const bool mine = (tid < 16);
                for (;;) {
                    unsigned v = tgt;
                    if (mine) v = ld_coh_u32(&barcnt[tid * 32]);
                    if (__all((int)(v >= tgt))) break;
                    __builtin_amdgcn_s_sleep(2);
                }
            }
            __syncthreads();
        }
    }
}

// ---------------------------------------------------------------------------
extern "C" void kernel_launch(void* const* d_in, const int* in_sizes, int n_in,
                              void* d_out, int out_size, void* d_ws, size_t ws_size,
                              hipStream_t stream)
{
    const float* x    = (const float*)d_in[0];
    const float* U0   = (const float*)d_in[1];
    const float* V0   = (const float*)d_in[2];
    const float* bih0 = (const float*)d_in[3];
    const float* bhh0 = (const float*)d_in[4];
    const float* U1   = (const float*)d_in[5];
    const float* V1   = (const float*)d_in[6];
    const float* bih1 = (const float*)d_in[7];
    const float* bhh1 = (const float*)d_in[8];

    char* ws = (char*)d_ws;
    short8*         Wf    = (short8*)(ws + OFF_WFRAG);
    __hip_bfloat16* xbf   = (__hip_bfloat16*)(ws + OFF_XBF);
    __hip_bfloat16* out0  = (__hip_bfloat16*)(ws + OFF_OUT0);
    __hip_bfloat16* hping = (__hip_bfloat16*)(ws + OFF_HPING);
    __hip_bfloat16* hzero = (__hip_bfloat16*)(ws + OFF_HZERO);
    float*          bias  = (float*)(ws + OFF_BIAS);
    unsigned*       barc  = (unsigned*)(ws + OFF_BAR);

    prep_misc<<<dim3(291), dim3(256), 0, stream>>>(bih0, bhh0, bih1, bhh1,
                                                   hzero, bias, barc);
    prep_x<<<dim3(32768), dim3(256), 0, stream>>>(x, xbf);
    prep_w<<<dim3(8192), dim3(256), 0, stream>>>(U0, V0, U1, V1, Wf);

    float* out1 = (float*)d_out;               // [512][64][1024]
    float* hfp  = out1 + 33554432;             // [2][64][1024]
    float* cfp  = hfp + 131072;                // [2][64][1024]

    void* kargs[] = { (void*)&xbf, (void*)&out0, (void*)&Wf, (void*)&bias,
                      (void*)&hzero, (void*)&hping, (void*)&out1,
                      (void*)&hfp, (void*)&cfp, (void*)&barc };
    hipLaunchCooperativeKernel((void*)lstm_persist, dim3(256), dim3(512),
                               kargs, 0, stream);
}

// Round 4
// 4693.095 us; speedup vs baseline: 6.1333x; 1.3757x over previous
//
#include <hip/hip_runtime.h>
#include <hip/hip_bf16.h>
#include <cstdint>
#include <cstddef>

// ---------------------------------------------------------------------------
// CustomLSTM: 2-layer LSTM, SEQ=512, B=64, IN=HS=1024.
// Round 5: wide-N blocks + small in-flight A set.
//   - Round 4 counters: VGPR_Count=120 < the 192 needed -> compiler serialized
//     the 32 A-loads into batches (multiple exposed MALL RTs); and 48 MB/step
//     of sc0sc1 A-broadcast hit the MALL. Fix: N=64 cols/block (16 units x 4
//     gates), M=32 rows -> A/block = 128 KB (24 MB/step total), and per wave
//     only 16 A-frags (64 VGPR) in flight with ONE vmcnt(0) drain.
//   - Weights: 32 frags = 128 VGPRs resident per wave for all 512 steps.
//   - Transposed LDS partial buffer -> ds_write_b64 pairs, ~2-way conflicts.
//   - Spread-counter MALL barrier (proven round 3/4).
// ---------------------------------------------------------------------------

typedef __attribute__((ext_vector_type(8))) short short8;     // 8 x bf16
typedef __attribute__((ext_vector_type(4))) float floatx4;    // MFMA acc

#define SEQL  512
#define BATCH 64
#define HSZ   1024
#define STEP_ELEMS 65536     // 64*1024, one timestep's h/x slab

// ---- workspace layout (bytes) ---------------------------------------------
#define OFF_WFRAG  ((size_t)0)            // 33,554,432
#define OFF_XBF    ((size_t)33554432)     // 67,108,864
#define OFF_OUT0   ((size_t)100663296)    // 67,108,864
#define OFF_HPING  ((size_t)167772160)    //    262,144
#define OFF_HZERO  ((size_t)168034304)    //    131,072
#define OFF_BIAS   ((size_t)168165376)    //     32,768
#define OFF_BAR    ((size_t)168198144)    //      2,048

// ---------------------------------------------------------------------------
// coherent (cross-XCD) access helpers: sc0 sc1 -> MALL coherence point.
// ---------------------------------------------------------------------------
__device__ __forceinline__ short8 ld16_coh(const __hip_bfloat16* p)
{
    short8 d;
    asm volatile("global_load_dwordx4 %0, %1, off sc0 sc1"
                 : "=v"(d) : "v"(p) : "memory");
    return d;
}

__device__ __forceinline__ unsigned ld_coh_u32(const unsigned* p)
{
    unsigned d;
    asm volatile("global_load_dword %0, %1, off sc0 sc1\n\t"
                 "s_waitcnt vmcnt(0)"
                 : "=v"(d) : "v"(p) : "memory");
    return d;
}

__device__ __forceinline__ void st_coh_u32(unsigned* p, unsigned v)
{
    asm volatile("global_store_dword %0, %1, off sc0 sc1"
                 :: "v"(p), "v"(v) : "memory");
}

// ---------------------------------------------------------------------------
// prep_misc: zero hzero + barrier counters, fuse biases. 291 x 256.
// ---------------------------------------------------------------------------
__global__ __launch_bounds__(256) void prep_misc(
    const float* __restrict__ bih0, const float* __restrict__ bhh0,
    const float* __restrict__ bih1, const float* __restrict__ bhh1,
    __hip_bfloat16* __restrict__ hzero, float* __restrict__ bias,
    unsigned* __restrict__ barcnt)
{
    int idx = blockIdx.x * 256 + threadIdx.x;
    if (idx < 65536) {
        hzero[idx] = __float2bfloat16(0.f);
    } else if (idx < 73728) {
        int rr = idx - 65536;
        int l = rr >> 12;
        int n = rr & 4095;
        bias[l * 4096 + n] = l ? (bih1[n] + bhh1[n]) : (bih0[n] + bhh0[n]);
    } else if (idx < 74240) {
        barcnt[idx - 73728] = 0u;
    }
}

// ---------------------------------------------------------------------------
// prep_x: fp32 -> bf16 conversion of the input tensor. 32768 x 256, 4/thread.
// ---------------------------------------------------------------------------
__global__ __launch_bounds__(256) void prep_x(
    const float* __restrict__ x, __hip_bfloat16* __restrict__ xbf)
{
    size_t i = ((size_t)blockIdx.x * 256 + threadIdx.x) * 4;
    float4 v = *(const float4*)(x + i);
    alignas(8) __hip_bfloat16 t[4];
    t[0] = __float2bfloat16(v.x);
    t[1] = __float2bfloat16(v.y);
    t[2] = __float2bfloat16(v.z);
    t[3] = __float2bfloat16(v.w);
    *(uint64_t*)(xbf + i) = *(const uint64_t*)t;
}

// ---------------------------------------------------------------------------
// prep_w: fragment-ordered bf16 weights.
// Unit-group g (0..63) owns hidden units g*16..+15; N-tile nt = gate (i,f,g,o),
// within-tile col = unit. Wave w owns kk = w*8 + kkl (kk = K/32 index).
// B-frag (16x16x32): col = lane&15, k = kk*32 + (lane>>4)*8 + j.
// W row = nt*1024 + g*16 + (lane&15);  k<1024 -> U, else V  (K = [x|h]).
// idx = (((((layer*64+g)*8+w)*4+nt)*8+kkl)*64+lane): 8192 x 256 threads.
// ---------------------------------------------------------------------------
__global__ __launch_bounds__(256) void prep_w(
    const float* __restrict__ U0, const float* __restrict__ V0,
    const float* __restrict__ U1, const float* __restrict__ V1,
    short8* __restrict__ Wf)
{
    int idx = blockIdx.x * 256 + threadIdx.x;   // 0..2,097,151
    int lane  = idx & 63;
    int kkl   = (idx >> 6) & 7;
    int nt    = (idx >> 9) & 3;
    int wv    = (idx >> 11) & 7;
    int g     = (idx >> 14) & 63;
    int layer = (idx >> 20) & 1;

    int kk   = wv * 8 + kkl;
    int wrow = nt * 1024 + g * 16 + (lane & 15);
    int k    = kk * 32 + ((lane >> 4) * 8);
    const float* U = layer ? U1 : U0;
    const float* V = layer ? V1 : V0;
    const float* src = (k < 1024) ? (U + (size_t)wrow * 1024 + k)
                                  : (V + (size_t)wrow * 1024 + (k - 1024));
    float4 v0 = *(const float4*)(src);
    float4 v1 = *(const float4*)(src + 4);
    alignas(16) __hip_bfloat16 t[8];
    t[0] = __float2bfloat16(v0.x); t[1] = __float2bfloat16(v0.y);
    t[2] = __float2bfloat16(v0.z); t[3] = __float2bfloat16(v0.w);
    t[4] = __float2bfloat16(v1.x); t[5] = __float2bfloat16(v1.y);
    t[6] = __float2bfloat16(v1.z); t[7] = __float2bfloat16(v1.w);
    Wf[idx] = *(const short8*)t;
}

// ---------------------------------------------------------------------------
// lstm_persist: whole 2-layer sequence, one launch, register-resident weights.
// blk = layer*128 + ms*64 + g. Block: batch rows ms*32..+31 (M=32), hidden
// units g*16..+15, all 4 gates (N=64). 8 waves K-split: wave w owns
// kk = w*8..w*8+7 (waves 0-3: x half, 4-7: h half). Per wave per step:
// 16 A-frags (one drain) -> 2mt x 4nt x 8kk = 64 MFMAs. Partials reduced
// 8-way in LDS (transposed layout), fused LSTM cell, 1 cell/thread.
// ---------------------------------------------------------------------------
__global__ __launch_bounds__(512, 2) void lstm_persist(
    const __hip_bfloat16* __restrict__ xbf,    // [512][64][1024] bf16
    __hip_bfloat16* __restrict__ out0,         // [512][64][1024] bf16 (L0 h)
    const short8* __restrict__ Wf,             // fragment weights
    const float* __restrict__ bias,            // [2][4096] fused bias
    const __hip_bfloat16* __restrict__ hzero,  // [64][1024] zeros
    __hip_bfloat16* __restrict__ hping,        // [2][64][1024] L1 h ping-pong
    float* __restrict__ out1,                  // [512][64][1024] fp32
    float* __restrict__ hf,                    // [2][64][1024] fp32
    float* __restrict__ cf,                    // [2][64][1024] fp32
    unsigned* __restrict__ barcnt)             // 16 counters, 128B stride
{
    __shared__ float Glds[8][64][36];          // [wave][col][row] transposed

    const int blk   = blockIdx.x;
    const int layer = blk >> 7;
    const int ms    = (blk >> 6) & 1;          // M-split (rows ms*32..+31)
    const int g     = blk & 63;                // unit group (16 units)
    const int tid   = threadIdx.x;
    const int lane  = tid & 63;
    const int w     = tid >> 6;
    const int xw    = (w < 4);                 // wave reads x-half of K?
    const int koff  = (w & 3) * 256 + ((lane >> 4) * 8);
    const int arow0 = ms * 32 + (lane & 15);
    const bool coh  = layer || !xw;            // cross-XCD data path?

    // ---- weight preload: 32 frags = 128 VGPRs, resident for 512 steps -----
    short8 wf[4][8];
    const size_t wbase = (((size_t)layer * 64 + g) * 8 + w) * 2048;
    #pragma unroll
    for (int nt = 0; nt < 4; ++nt)
        #pragma unroll
        for (int kkl = 0; kkl < 8; ++kkl)
            wf[nt][kkl] = Wf[wbase + (size_t)(nt * 512 + kkl * 64 + lane)];

    // ---- cell-phase constants: thread owns (local row cr, unit cu) --------
    const int cr = tid >> 4;                   // 0..31
    const int cu = tid & 15;                   // 0..15
    const int grow = ms * 32 + cr;             // global batch row
    const int j  = g * 16 + cu;                // global hidden unit
    const float bi  = bias[layer * 4096 + j];
    const float bfv = bias[layer * 4096 + 1024 + j];
    const float bg  = bias[layer * 4096 + 2048 + j];
    const float bo  = bias[layer * 4096 + 3072 + j];
    float c_reg = 0.f;                         // cell state, 512 steps

    for (int u = 0; u <= SEQL; ++u) {
        const int t = layer ? (u - 1) : u;
        const bool active = layer ? (u >= 1) : (u < SEQL);
        if (active) {
            const __hip_bfloat16* xpart =
                layer ? (out0 + (size_t)t * STEP_ELEMS)
                      : (xbf + (size_t)t * STEP_ELEMS);
            const __hip_bfloat16* hprev =
                (t == 0) ? hzero
                         : (layer ? (hping + (size_t)((t - 1) & 1) * STEP_ELEMS)
                                  : (out0 + (size_t)(t - 1) * STEP_ELEMS));
            const __hip_bfloat16* abase =
                (xw ? xpart : hprev) + (size_t)arow0 * 1024 + koff;

            // ---- 16 A-fragments straight to registers, ONE drain ----------
            short8 a[2][8];
            if (coh) {
                #pragma unroll
                for (int mt = 0; mt < 2; ++mt)
                    #pragma unroll
                    for (int kkl = 0; kkl < 8; ++kkl)
                        a[mt][kkl] = ld16_coh(abase + mt * 16384 + kkl * 32);
                asm volatile("s_waitcnt vmcnt(0)" ::: "memory");
                __builtin_amdgcn_sched_barrier(0);
            } else {
                #pragma unroll
                for (int mt = 0; mt < 2; ++mt)
                    #pragma unroll
                    for (int kkl = 0; kkl < 8; ++kkl)
                        a[mt][kkl] =
                            *(const short8*)(abase + mt * 16384 + kkl * 32);
            }

            // ---- 64 register-only MFMAs -----------------------------------
            floatx4 acc[2][4];
            #pragma unroll
            for (int mt = 0; mt < 2; ++mt)
                #pragma unroll
                for (int nt = 0; nt < 4; ++nt)
                    acc[mt][nt] = (floatx4){0.f, 0.f, 0.f, 0.f};
            #pragma unroll
            for (int kkl = 0; kkl < 8; ++kkl)
                #pragma unroll
                for (int mt = 0; mt < 2; ++mt)
                    #pragma unroll
                    for (int nt = 0; nt < 4; ++nt)
                        acc[mt][nt] = __builtin_amdgcn_mfma_f32_16x16x32_bf16(
                            a[mt][kkl], wf[nt][kkl], acc[mt][nt], 0, 0, 0);

            // ---- K-partials to LDS, transposed: [w][col][row], b64 pairs --
            {
                const int col = lane & 15;
                const int rq  = (lane >> 4) * 4;
                #pragma unroll
                for (int mt = 0; mt < 2; ++mt)
                    #pragma unroll
                    for (int nt = 0; nt < 4; ++nt) {
                        float* base = &Glds[w][nt * 16 + col][mt * 16 + rq];
                        *(float2*)(base)     = (float2){acc[mt][nt][0],
                                                        acc[mt][nt][1]};
                        *(float2*)(base + 2) = (float2){acc[mt][nt][2],
                                                        acc[mt][nt][3]};
                    }
            }
            __syncthreads();

            // ---- 8-way reduce + fused LSTM cell ---------------------------
            {
                float v0 = 0.f, v1 = 0.f, v2 = 0.f, v3 = 0.f;
                #pragma unroll
                for (int ww = 0; ww < 8; ++ww) {
                    v0 += Glds[ww][cu][cr];          // gate i  (col = 0+cu)
                    v1 += Glds[ww][16 + cu][cr];     // gate f
                    v2 += Glds[ww][32 + cu][cr];     // gate g
                    v3 += Glds[ww][48 + cu][cr];     // gate o
                }
                float iv = 1.f / (1.f + __expf(-(v0 + bi)));
                float fv = 1.f / (1.f + __expf(-(v1 + bfv)));
                float gv = tanhf(v2 + bg);
                float ov = 1.f / (1.f + __expf(-(v3 + bo)));
                float cn = fv * c_reg + iv * gv;
                float hn = ov * tanhf(cn);
                c_reg = cn;

                __hip_bfloat16 hb = __float2bfloat16(hn);
                unsigned hu = *(const unsigned short*)&hb;
                unsigned other = (unsigned)__shfl_xor((int)hu, 1);
                if (!(cu & 1)) {
                    unsigned pack = hu | (other << 16);
                    __hip_bfloat16* hout =
                        layer ? (hping + (size_t)(t & 1) * STEP_ELEMS)
                              : (out0 + (size_t)t * STEP_ELEMS);
                    st_coh_u32((unsigned*)(hout + (size_t)grow * 1024 + j),
                               pack);
                }
                if (layer)
                    __builtin_nontemporal_store(
                        hn, out1 + (size_t)t * STEP_ELEMS + grow * 1024 + j);
                if (t == SEQL - 1) {
                    __builtin_nontemporal_store(
                        hn, hf + (size_t)layer * STEP_ELEMS + grow * 1024 + j);
                    __builtin_nontemporal_store(
                        cn, cf + (size_t)layer * STEP_ELEMS + grow * 1024 + j);
                }
            }
        }

        // ---- MALL barrier (no cache invalidation) -------------------------
        if (u < SEQL) {
            asm volatile("s_waitcnt vmcnt(0)" ::: "memory");  // drain h-stores
            __syncthreads();
            if (tid == 0)
                __hip_atomic_fetch_add(&barcnt[(blk & 15) * 32], 1u,
                                       __ATOMIC_RELAXED,
                                       __HIP_MEMORY_SCOPE_AGENT);
            if (tid < 64) {
                const unsigned tgt = (unsigned)(u + 1) * 16u;
                const bool mine = (tid < 16);
                for (;;) {
                    unsigned v = tgt;
                    if (mine) v = ld_coh_u32(&barcnt[tid * 32]);
                    if (__all((int)(v >= tgt))) break;
                    __builtin_amdgcn_s_sleep(1);
                }
            }
            __syncthreads();
        }
    }
}

// ---------------------------------------------------------------------------
extern "C" void kernel_launch(void* const* d_in, const int* in_sizes, int n_in,
                              void* d_out, int out_size, void* d_ws, size_t ws_size,
                              hipStream_t stream)
{
    const float* x    = (const float*)d_in[0];
    const float* U0   = (const float*)d_in[1];
    const float* V0   = (const float*)d_in[2];
    const float* bih0 = (const float*)d_in[3];
    const float* bhh0 = (const float*)d_in[4];
    const float* U1   = (const float*)d_in[5];
    const float* V1   = (const float*)d_in[6];
    const float* bih1 = (const float*)d_in[7];
    const float* bhh1 = (const float*)d_in[8];

    char* ws = (char*)d_ws;
    short8*         Wf    = (short8*)(ws + OFF_WFRAG);
    __hip_bfloat16* xbf   = (__hip_bfloat16*)(ws + OFF_XBF);
    __hip_bfloat16* out0  = (__hip_bfloat16*)(ws + OFF_OUT0);
    __hip_bfloat16* hping = (__hip_bfloat16*)(ws + OFF_HPING);
    __hip_bfloat16* hzero = (__hip_bfloat16*)(ws + OFF_HZERO);
    float*          bias  = (float*)(ws + OFF_BIAS);
    unsigned*       barc  = (unsigned*)(ws + OFF_BAR);

    prep_misc<<<dim3(291), dim3(256), 0, stream>>>(bih0, bhh0, bih1, bhh1,
                                                   hzero, bias, barc);
    prep_x<<<dim3(32768), dim3(256), 0, stream>>>(x, xbf);
    prep_w<<<dim3(8192), dim3(256), 0, stream>>>(U0, V0, U1, V1, Wf);

    float* out1 = (float*)d_out;               // [512][64][1024]
    float* hfp  = out1 + 33554432;             // [2][64][1024]
    float* cfp  = hfp + 131072;                // [2][64][1024]

    void* kargs[] = { (void*)&xbf, (void*)&out0, (void*)&Wf, (void*)&bias,
                      (void*)&hzero, (void*)&hping, (void*)&out1,
                      (void*)&hfp, (void*)&cfp, (void*)&barc };
    hipLaunchCooperativeKernel((void*)lstm_persist, dim3(256), dim3(512),
                               kargs, 0, stream);
}

// Round 5
// 4459.910 us; speedup vs baseline: 6.4540x; 1.0523x over previous
//
#include <hip/hip_runtime.h>
#include <hip/hip_bf16.h>
#include <cstdint>
#include <cstddef>

// ---------------------------------------------------------------------------
// CustomLSTM: 2-layer LSTM, SEQ=512, B=64, IN=HS=1024.
// Round 6: decoupled flag-based sync (no global barrier, no atomics).
//   - Batch rows are independent -> two fully independent groups (rows 0-31 /
//     32-63), each with its own flag set. Within a group L0 free-runs its own
//     recurrence (polls only L0 flags); L1 chases (polls L0+L1 flags).
//     Removes max-of-256 skew coupling and the L0-waits-for-L1 systematic
//     stall of the single global barrier.
//   - Arrival atomic (1 RT + 16-way MALL serialization) replaced by per-block
//     flag stores; consumers poll 64 packed flags with ONE 64-lane dwordx2
//     coherent load per round.
//   - L0 x-waves prefetch their (static) A-frags before the poll.
//   - GEMM core unchanged from round 5: weights VGPR-resident (32 frags),
//     16 A-frags/wave with one drain, 64 MFMAs, transposed LDS reduce.
// ---------------------------------------------------------------------------

typedef __attribute__((ext_vector_type(8))) short short8;     // 8 x bf16
typedef __attribute__((ext_vector_type(4))) float floatx4;    // MFMA acc

#define SEQL  512
#define BATCH 64
#define HSZ   1024
#define STEP_ELEMS 65536     // 64*1024, one timestep's h/x slab

// ---- workspace layout (bytes) ---------------------------------------------
#define OFF_WFRAG  ((size_t)0)            // 33,554,432
#define OFF_XBF    ((size_t)33554432)     // 67,108,864
#define OFF_OUT0   ((size_t)100663296)    // 67,108,864
#define OFF_HPING  ((size_t)167772160)    //    262,144
#define OFF_HZERO  ((size_t)168034304)    //    131,072
#define OFF_BIAS   ((size_t)168165376)    //     32,768
#define OFF_BAR    ((size_t)168198144)    //      2,048 (flags: 256 dwords)

// ---------------------------------------------------------------------------
// coherent (cross-XCD) access helpers: sc0 sc1 -> MALL coherence point.
// ---------------------------------------------------------------------------
__device__ __forceinline__ short8 ld16_coh(const __hip_bfloat16* p)
{
    short8 d;
    asm volatile("global_load_dwordx4 %0, %1, off sc0 sc1"
                 : "=v"(d) : "v"(p) : "memory");
    return d;
}

__device__ __forceinline__ unsigned long long ld_coh_u64(const unsigned* p)
{
    unsigned long long d;
    asm volatile("global_load_dwordx2 %0, %1, off sc0 sc1\n\t"
                 "s_waitcnt vmcnt(0)"
                 : "=v"(d) : "v"(p) : "memory");
    return d;
}

__device__ __forceinline__ void st_coh_u32(unsigned* p, unsigned v)
{
    asm volatile("global_store_dword %0, %1, off sc0 sc1"
                 :: "v"(p), "v"(v) : "memory");
}

// ---------------------------------------------------------------------------
// prep_misc: zero hzero + flags, fuse biases. 291 x 256.
// ---------------------------------------------------------------------------
__global__ __launch_bounds__(256) void prep_misc(
    const float* __restrict__ bih0, const float* __restrict__ bhh0,
    const float* __restrict__ bih1, const float* __restrict__ bhh1,
    __hip_bfloat16* __restrict__ hzero, float* __restrict__ bias,
    unsigned* __restrict__ flags)
{
    int idx = blockIdx.x * 256 + threadIdx.x;
    if (idx < 65536) {
        hzero[idx] = __float2bfloat16(0.f);
    } else if (idx < 73728) {
        int rr = idx - 65536;
        int l = rr >> 12;
        int n = rr & 4095;
        bias[l * 4096 + n] = l ? (bih1[n] + bhh1[n]) : (bih0[n] + bhh0[n]);
    } else if (idx < 74240) {
        flags[idx - 73728] = 0u;
    }
}

// ---------------------------------------------------------------------------
// prep_x: fp32 -> bf16 conversion of the input tensor. 32768 x 256, 4/thread.
// ---------------------------------------------------------------------------
__global__ __launch_bounds__(256) void prep_x(
    const float* __restrict__ x, __hip_bfloat16* __restrict__ xbf)
{
    size_t i = ((size_t)blockIdx.x * 256 + threadIdx.x) * 4;
    float4 v = *(const float4*)(x + i);
    alignas(8) __hip_bfloat16 t[4];
    t[0] = __float2bfloat16(v.x);
    t[1] = __float2bfloat16(v.y);
    t[2] = __float2bfloat16(v.z);
    t[3] = __float2bfloat16(v.w);
    *(uint64_t*)(xbf + i) = *(const uint64_t*)t;
}

// ---------------------------------------------------------------------------
// prep_w: fragment-ordered bf16 weights (UNCHANGED from round 5).
// Unit-group g (0..63) owns hidden units g*16..+15; N-tile nt = gate (i,f,g,o).
// Wave w owns kk = w*8 + kkl. B-frag: col = lane&15, k = kk*32+(lane>>4)*8+j.
// W row = nt*1024 + g*16 + (lane&15);  k<1024 -> U, else V  (K = [x|h]).
// ---------------------------------------------------------------------------
__global__ __launch_bounds__(256) void prep_w(
    const float* __restrict__ U0, const float* __restrict__ V0,
    const float* __restrict__ U1, const float* __restrict__ V1,
    short8* __restrict__ Wf)
{
    int idx = blockIdx.x * 256 + threadIdx.x;   // 0..2,097,151
    int lane  = idx & 63;
    int kkl   = (idx >> 6) & 7;
    int nt    = (idx >> 9) & 3;
    int wv    = (idx >> 11) & 7;
    int g     = (idx >> 14) & 63;
    int layer = (idx >> 20) & 1;

    int kk   = wv * 8 + kkl;
    int wrow = nt * 1024 + g * 16 + (lane & 15);
    int k    = kk * 32 + ((lane >> 4) * 8);
    const float* U = layer ? U1 : U0;
    const float* V = layer ? V1 : V0;
    const float* src = (k < 1024) ? (U + (size_t)wrow * 1024 + k)
                                  : (V + (size_t)wrow * 1024 + (k - 1024));
    float4 v0 = *(const float4*)(src);
    float4 v1 = *(const float4*)(src + 4);
    alignas(16) __hip_bfloat16 t[8];
    t[0] = __float2bfloat16(v0.x); t[1] = __float2bfloat16(v0.y);
    t[2] = __float2bfloat16(v0.z); t[3] = __float2bfloat16(v0.w);
    t[4] = __float2bfloat16(v1.x); t[5] = __float2bfloat16(v1.y);
    t[6] = __float2bfloat16(v1.z); t[7] = __float2bfloat16(v1.w);
    Wf[idx] = *(const short8*)t;
}

// ---------------------------------------------------------------------------
// lstm_persist: whole 2-layer sequence, one launch.
// blk = grp*128 + layer*64 + ng. Block: batch rows grp*32..+31, hidden units
// ng*16..+15, all 4 gates (N=64). 8 waves K-split (waves 0-3: x half, 4-7:
// h half). Sync: per-(grp,ng) flag pair {fL0,fL1}; L0 polls fL0[0..63] >= u,
// L1 polls fL0 & fL1 >= u. Groups are fully independent.
// ---------------------------------------------------------------------------
__global__ __launch_bounds__(512, 2) void lstm_persist(
    const __hip_bfloat16* __restrict__ xbf,    // [512][64][1024] bf16
    __hip_bfloat16* __restrict__ out0,         // [512][64][1024] bf16 (L0 h)
    const short8* __restrict__ Wf,             // fragment weights
    const float* __restrict__ bias,            // [2][4096] fused bias
    const __hip_bfloat16* __restrict__ hzero,  // [64][1024] zeros
    __hip_bfloat16* __restrict__ hping,        // [2][64][1024] L1 h ping-pong
    float* __restrict__ out1,                  // [512][64][1024] fp32
    float* __restrict__ hf,                    // [2][64][1024] fp32
    float* __restrict__ cf,                    // [2][64][1024] fp32
    unsigned* __restrict__ flags)              // [2][64][2] step flags
{
    __shared__ float Glds[8][64][36];          // [wave][col][row] transposed

    const int blk   = blockIdx.x;
    const int grp   = blk >> 7;                // batch group (rows grp*32..+31)
    const int layer = (blk >> 6) & 1;
    const int ng    = blk & 63;                // unit group (16 units)
    const int tid   = threadIdx.x;
    const int lane  = tid & 63;
    const int w     = tid >> 6;
    const int xw    = (w < 4);                 // wave reads x-half of K?
    const int koff  = (w & 3) * 256 + ((lane >> 4) * 8);
    const int arow0 = grp * 32 + (lane & 15);
    const bool coh  = layer || !xw;            // cross-XCD data path?

    // ---- weight preload: 32 frags = 128 VGPRs, resident for 512 steps -----
    short8 wf[4][8];
    const size_t wbase = (((size_t)layer * 64 + ng) * 8 + w) * 2048;
    #pragma unroll
    for (int nt = 0; nt < 4; ++nt)
        #pragma unroll
        for (int kkl = 0; kkl < 8; ++kkl)
            wf[nt][kkl] = Wf[wbase + (size_t)(nt * 512 + kkl * 64 + lane)];

    // ---- cell-phase constants: thread owns (local row cr, unit cu) --------
    const int cr = tid >> 4;                   // 0..31
    const int cu = tid & 15;                   // 0..15
    const int grow = grp * 32 + cr;            // global batch row
    const int j  = ng * 16 + cu;               // global hidden unit
    const float bi  = bias[layer * 4096 + j];
    const float bfv = bias[layer * 4096 + 1024 + j];
    const float bg  = bias[layer * 4096 + 2048 + j];
    const float bo  = bias[layer * 4096 + 3072 + j];
    float c_reg = 0.f;                         // cell state, 512 steps

    unsigned* myflag = flags + (((size_t)grp * 64 + ng) * 2 + layer);
    const unsigned* fpoll = flags + ((size_t)grp * 64 + lane) * 2;

    for (int u = 0; u <= SEQL; ++u) {
        const int t = layer ? (u - 1) : u;
        const bool active = layer ? (u >= 1) : (u < SEQL);

        short8 a[2][8];
        // ---- L0 x-waves: static data, prefetch BEFORE the poll ------------
        if (active && !coh) {
            const __hip_bfloat16* abase =
                xbf + (size_t)t * STEP_ELEMS + (size_t)arow0 * 1024 + koff;
            #pragma unroll
            for (int mt = 0; mt < 2; ++mt)
                #pragma unroll
                for (int kkl = 0; kkl < 8; ++kkl)
                    a[mt][kkl] =
                        *(const short8*)(abase + mt * 16384 + kkl * 32);
        }

        // ---- dependency poll (flag-based, layer-decoupled) ----------------
        if (u > 0) {
            if (tid < 64) {
                const unsigned need = (unsigned)u;
                for (;;) {
                    unsigned long long f = ld_coh_u64(fpoll);
                    unsigned f0 = (unsigned)f;
                    unsigned f1 = (unsigned)(f >> 32);
                    bool ok = (f0 >= need) && (!layer || f1 >= need);
                    if (__all((int)ok)) break;
                    __builtin_amdgcn_s_sleep(1);
                }
            }
            __syncthreads();
        }

        if (active) {
            // ---- coherent A-fragments (h half / all of L1), ONE drain -----
            if (coh) {
                const __hip_bfloat16* xpart =
                    layer ? (out0 + (size_t)t * STEP_ELEMS)
                          : (xbf + (size_t)t * STEP_ELEMS);
                const __hip_bfloat16* hprev =
                    (t == 0) ? hzero
                             : (layer ? (hping +
                                         (size_t)((t - 1) & 1) * STEP_ELEMS)
                                      : (out0 +
                                         (size_t)(t - 1) * STEP_ELEMS));
                const __hip_bfloat16* abase =
                    (xw ? xpart : hprev) + (size_t)arow0 * 1024 + koff;
                #pragma unroll
                for (int mt = 0; mt < 2; ++mt)
                    #pragma unroll
                    for (int kkl = 0; kkl < 8; ++kkl)
                        a[mt][kkl] = ld16_coh(abase + mt * 16384 + kkl * 32);
                asm volatile("s_waitcnt vmcnt(0)" ::: "memory");
                __builtin_amdgcn_sched_barrier(0);
            }

            // ---- 64 register-only MFMAs -----------------------------------
            floatx4 acc[2][4];
            #pragma unroll
            for (int mt = 0; mt < 2; ++mt)
                #pragma unroll
                for (int nt = 0; nt < 4; ++nt)
                    acc[mt][nt] = (floatx4){0.f, 0.f, 0.f, 0.f};
            #pragma unroll
            for (int kkl = 0; kkl < 8; ++kkl)
                #pragma unroll
                for (int mt = 0; mt < 2; ++mt)
                    #pragma unroll
                    for (int nt = 0; nt < 4; ++nt)
                        acc[mt][nt] = __builtin_amdgcn_mfma_f32_16x16x32_bf16(
                            a[mt][kkl], wf[nt][kkl], acc[mt][nt], 0, 0, 0);

            // ---- K-partials to LDS, transposed: [w][col][row], b64 pairs --
            {
                const int col = lane & 15;
                const int rq  = (lane >> 4) * 4;
                #pragma unroll
                for (int mt = 0; mt < 2; ++mt)
                    #pragma unroll
                    for (int nt = 0; nt < 4; ++nt) {
                        float* base = &Glds[w][nt * 16 + col][mt * 16 + rq];
                        *(float2*)(base)     = (float2){acc[mt][nt][0],
                                                        acc[mt][nt][1]};
                        *(float2*)(base + 2) = (float2){acc[mt][nt][2],
                                                        acc[mt][nt][3]};
                    }
            }
            __syncthreads();

            // ---- 8-way reduce + fused LSTM cell ---------------------------
            {
                float v0 = 0.f, v1 = 0.f, v2 = 0.f, v3 = 0.f;
                #pragma unroll
                for (int ww = 0; ww < 8; ++ww) {
                    v0 += Glds[ww][cu][cr];          // gate i
                    v1 += Glds[ww][16 + cu][cr];     // gate f
                    v2 += Glds[ww][32 + cu][cr];     // gate g
                    v3 += Glds[ww][48 + cu][cr];     // gate o
                }
                float iv = 1.f / (1.f + __expf(-(v0 + bi)));
                float fv = 1.f / (1.f + __expf(-(v1 + bfv)));
                float gv = tanhf(v2 + bg);
                float ov = 1.f / (1.f + __expf(-(v3 + bo)));
                float cn = fv * c_reg + iv * gv;
                float hn = ov * tanhf(cn);
                c_reg = cn;

                __hip_bfloat16 hb = __float2bfloat16(hn);
                unsigned hu = *(const unsigned short*)&hb;
                unsigned other = (unsigned)__shfl_xor((int)hu, 1);
                if (!(cu & 1)) {
                    unsigned pack = hu | (other << 16);
                    __hip_bfloat16* hout =
                        layer ? (hping + (size_t)(t & 1) * STEP_ELEMS)
                              : (out0 + (size_t)t * STEP_ELEMS);
                    st_coh_u32((unsigned*)(hout + (size_t)grow * 1024 + j),
                               pack);
                }
                if (layer)
                    __builtin_nontemporal_store(
                        hn, out1 + (size_t)t * STEP_ELEMS + grow * 1024 + j);
                if (t == SEQL - 1) {
                    __builtin_nontemporal_store(
                        hn, hf + (size_t)layer * STEP_ELEMS + grow * 1024 + j);
                    __builtin_nontemporal_store(
                        cn, cf + (size_t)layer * STEP_ELEMS + grow * 1024 + j);
                }
            }
        }

        // ---- publish: drain h-stores, then flag (no atomics) --------------
        asm volatile("s_waitcnt vmcnt(0)" ::: "memory");
        __syncthreads();
        if (u < SEQL && tid == 0)
            st_coh_u32(myflag, (unsigned)(u + 1));
    }
}

// ---------------------------------------------------------------------------
extern "C" void kernel_launch(void* const* d_in, const int* in_sizes, int n_in,
                              void* d_out, int out_size, void* d_ws, size_t ws_size,
                              hipStream_t stream)
{
    const float* x    = (const float*)d_in[0];
    const float* U0   = (const float*)d_in[1];
    const float* V0   = (const float*)d_in[2];
    const float* bih0 = (const float*)d_in[3];
    const float* bhh0 = (const float*)d_in[4];
    const float* U1   = (const float*)d_in[5];
    const float* V1   = (const float*)d_in[6];
    const float* bih1 = (const float*)d_in[7];
    const float* bhh1 = (const float*)d_in[8];

    char* ws = (char*)d_ws;
    short8*         Wf    = (short8*)(ws + OFF_WFRAG);
    __hip_bfloat16* xbf   = (__hip_bfloat16*)(ws + OFF_XBF);
    __hip_bfloat16* out0  = (__hip_bfloat16*)(ws + OFF_OUT0);
    __hip_bfloat16* hping = (__hip_bfloat16*)(ws + OFF_HPING);
    __hip_bfloat16* hzero = (__hip_bfloat16*)(ws + OFF_HZERO);
    float*          bias  = (float*)(ws + OFF_BIAS);
    unsigned*       flg   = (unsigned*)(ws + OFF_BAR);

    prep_misc<<<dim3(291), dim3(256), 0, stream>>>(bih0, bhh0, bih1, bhh1,
                                                   hzero, bias, flg);
    prep_x<<<dim3(32768), dim3(256), 0, stream>>>(x, xbf);
    prep_w<<<dim3(8192), dim3(256), 0, stream>>>(U0, V0, U1, V1, Wf);

    float* out1 = (float*)d_out;               // [512][64][1024]
    float* hfp  = out1 + 33554432;             // [2][64][1024]
    float* cfp  = hfp + 131072;                // [2][64][1024]

    void* kargs[] = { (void*)&xbf, (void*)&out0, (void*)&Wf, (void*)&bias,
                      (void*)&hzero, (void*)&hping, (void*)&out1,
                      (void*)&hfp, (void*)&cfp, (void*)&flg };
    hipLaunchCooperativeKernel((void*)lstm_persist, dim3(256), dim3(512),
                               kargs, 0, stream);
}

// Round 7
// 3450.320 us; speedup vs baseline: 8.3425x; 1.2926x over previous
//
#include <hip/hip_runtime.h>
#include <hip/hip_bf16.h>
#include <cstdint>
#include <cstddef>

// ---------------------------------------------------------------------------
// CustomLSTM: 2-layer LSTM, SEQ=512, B=64, IN=HS=1024.
// Round 7: forced weight residency + L2-cacheable out0 + per-wave polls.
//   - Rounds 4/5 showed VGPR_Count=128 < the ~240 the design needs: weights
//     were NEVER register-resident (re-fetched per step). Fix: volatile-asm
//     weight loads (non-rematerializable) + single drain before the loop.
//   - out0 slab addresses are never reused -> consumers read them with sc0
//     (L2-CACHEABLE): first reader per XCD pulls from MALL, the rest hit the
//     local L2. Free 8-16x dedup of the h broadcast, no staging protocol.
//     Producers write through (sc0 sc1). hping (address-reused) stays sc0sc1.
//   - h slabs in block-contiguous plane layout [ng][row][cu]: single-writer
//     full lines, contiguous 16-B fragments.
//   - Per-wave dependency polls (L0 x-waves never poll); one less sync;
//     out1/hf/cf stores deferred after flag publish. hzero dropped (t==0 ->
//     zero A registers; numerically identical).
//   - Flag scheme, GEMM decomposition, cell math: unchanged from round 5.
// ---------------------------------------------------------------------------

typedef __attribute__((ext_vector_type(8))) short short8;     // 8 x bf16
typedef __attribute__((ext_vector_type(4))) float floatx4;    // MFMA acc

#define SEQL  512
#define HSZ   1024
#define STEP_ELEMS 65536     // 64*1024, one timestep's h/x slab

// ---- workspace layout (bytes) ---------------------------------------------
#define OFF_WFRAG  ((size_t)0)            // 33,554,432
#define OFF_XBF    ((size_t)33554432)     // 67,108,864
#define OFF_OUT0   ((size_t)100663296)    // 67,108,864  (plane layout)
#define OFF_HPING  ((size_t)167772160)    //    262,144  (plane layout)
#define OFF_BIAS   ((size_t)168165376)    //     32,768
#define OFF_FLAGS  ((size_t)168198144)    //      1,024  ([cls][grp][ng])

// ---------------------------------------------------------------------------
// memory helpers
// ---------------------------------------------------------------------------
// weights: plain cached load, volatile so it cannot be rematerialized in-loop
__device__ __forceinline__ short8 ld16_wt(const short8* p)
{
    short8 d;
    asm volatile("global_load_dwordx4 %0, %1, off" : "=v"(d) : "v"(p));
    return d;
}
// out0 consumer: L1-bypass, L2-CACHEABLE (fresh addresses -> coherent)
__device__ __forceinline__ short8 ld16_l2(const __hip_bfloat16* p)
{
    short8 d;
    asm volatile("global_load_dwordx4 %0, %1, off sc0" : "=v"(d) : "v"(p));
    return d;
}
// hping consumer: MALL coherence point (addresses reused)
__device__ __forceinline__ short8 ld16_coh(const __hip_bfloat16* p)
{
    short8 d;
    asm volatile("global_load_dwordx4 %0, %1, off sc0 sc1" : "=v"(d) : "v"(p));
    return d;
}
__device__ __forceinline__ unsigned ld_coh_u32(const unsigned* p)
{
    unsigned d;
    asm volatile("global_load_dword %0, %1, off sc0 sc1\n\t"
                 "s_waitcnt vmcnt(0)"
                 : "=v"(d) : "v"(p) : "memory");
    return d;
}
__device__ __forceinline__ void st_coh_u32(unsigned* p, unsigned v)
{
    asm volatile("global_store_dword %0, %1, off sc0 sc1"
                 :: "v"(p), "v"(v) : "memory");
}

// ---------------------------------------------------------------------------
// prep_misc: fuse biases, zero flags. 33 x 256.
// ---------------------------------------------------------------------------
__global__ __launch_bounds__(256) void prep_misc(
    const float* __restrict__ bih0, const float* __restrict__ bhh0,
    const float* __restrict__ bih1, const float* __restrict__ bhh1,
    float* __restrict__ bias, unsigned* __restrict__ flags)
{
    int idx = blockIdx.x * 256 + threadIdx.x;
    if (idx < 8192) {
        int l = idx >> 12;
        int n = idx & 4095;
        bias[l * 4096 + n] = l ? (bih1[n] + bhh1[n]) : (bih0[n] + bhh0[n]);
    } else if (idx < 8448) {
        flags[idx - 8192] = 0u;
    }
}

// ---------------------------------------------------------------------------
// prep_x: fp32 -> bf16 conversion of the input tensor (row-major).
// ---------------------------------------------------------------------------
__global__ __launch_bounds__(256) void prep_x(
    const float* __restrict__ x, __hip_bfloat16* __restrict__ xbf)
{
    size_t i = ((size_t)blockIdx.x * 256 + threadIdx.x) * 4;
    float4 v = *(const float4*)(x + i);
    alignas(8) __hip_bfloat16 t[4];
    t[0] = __float2bfloat16(v.x);
    t[1] = __float2bfloat16(v.y);
    t[2] = __float2bfloat16(v.z);
    t[3] = __float2bfloat16(v.w);
    *(uint64_t*)(xbf + i) = *(const uint64_t*)t;
}

// ---------------------------------------------------------------------------
// prep_w: fragment-ordered bf16 weights (UNCHANGED from round 5 — proven).
// Unit-group g owns units g*16..+15; N-tile nt = gate; wave w owns kk=w*8+kkl.
// B-frag: col = lane&15, k = kk*32 + (lane>>4)*8 + j.
// W row = nt*1024 + g*16 + (lane&15); k<1024 -> U else V (K = [x|h]).
// ---------------------------------------------------------------------------
__global__ __launch_bounds__(256) void prep_w(
    const float* __restrict__ U0, const float* __restrict__ V0,
    const float* __restrict__ U1, const float* __restrict__ V1,
    short8* __restrict__ Wf)
{
    int idx = blockIdx.x * 256 + threadIdx.x;   // 0..2,097,151
    int lane  = idx & 63;
    int kkl   = (idx >> 6) & 7;
    int nt    = (idx >> 9) & 3;
    int wv    = (idx >> 11) & 7;
    int g     = (idx >> 14) & 63;
    int layer = (idx >> 20) & 1;

    int kk   = wv * 8 + kkl;
    int wrow = nt * 1024 + g * 16 + (lane & 15);
    int k    = kk * 32 + ((lane >> 4) * 8);
    const float* U = layer ? U1 : U0;
    const float* V = layer ? V1 : V0;
    const float* src = (k < 1024) ? (U + (size_t)wrow * 1024 + k)
                                  : (V + (size_t)wrow * 1024 + (k - 1024));
    float4 v0 = *(const float4*)(src);
    float4 v1 = *(const float4*)(src + 4);
    alignas(16) __hip_bfloat16 t[8];
    t[0] = __float2bfloat16(v0.x); t[1] = __float2bfloat16(v0.y);
    t[2] = __float2bfloat16(v0.z); t[3] = __float2bfloat16(v0.w);
    t[4] = __float2bfloat16(v1.x); t[5] = __float2bfloat16(v1.y);
    t[6] = __float2bfloat16(v1.z); t[7] = __float2bfloat16(v1.w);
    Wf[idx] = *(const short8*)t;
}

// ---------------------------------------------------------------------------
// lstm_persist: whole 2-layer sequence, one launch.
// blk = grp*128 + layer*64 + ng. Block: rows grp*32..+31, units ng*16..+15,
// all 4 gates (N=64). 8 waves K-split (w 0-3: x half, 4-7: h half).
// h slabs plane layout: elem = ng*1024 + row*16 + cu.
// Flags: flags[cls*128 + grp*64 + ng] = steps completed by that block.
// ---------------------------------------------------------------------------
__global__ __launch_bounds__(512, 2) void lstm_persist(
    const __hip_bfloat16* __restrict__ xbf,    // [512][row][1024] bf16
    __hip_bfloat16* __restrict__ out0,         // [512] plane slabs (L0 h)
    const short8* __restrict__ Wf,
    const float* __restrict__ bias,            // [2][4096]
    __hip_bfloat16* __restrict__ hping,        // [2] plane slabs (L1 h)
    float* __restrict__ out1,                  // [512][row][1024] fp32
    float* __restrict__ hf,
    float* __restrict__ cfin,
    unsigned* __restrict__ flags)
{
    __shared__ float Glds[8][64][36];          // [wave][col][row] transposed

    const int blk   = blockIdx.x;
    const int grp   = blk >> 7;
    const int layer = (blk >> 6) & 1;
    const int ng    = blk & 63;
    const int tid   = threadIdx.x;
    const int lane  = tid & 63;
    const int w     = tid >> 6;
    const int xw    = (w < 4);                 // x-half wave?
    const int kb    = (w & 3) * 256 + ((lane >> 4) * 8);  // unit base (half-K)
    const int rb    = grp * 32 + (lane & 15);  // + mt*16 -> global row

    // ---- weight preload: 32 frags = 128 VGPRs, FORCED resident ------------
    short8 wf[4][8];
    {
        const short8* wp = Wf + (((size_t)layer * 64 + ng) * 8 + w) * 2048;
        #pragma unroll
        for (int nt = 0; nt < 4; ++nt)
            #pragma unroll
            for (int kkl = 0; kkl < 8; ++kkl)
                wf[nt][kkl] = ld16_wt(wp + nt * 512 + kkl * 64 + lane);
        asm volatile("s_waitcnt vmcnt(0)" ::: "memory");
    }

    // ---- cell-phase constants: thread owns (local row cr, unit cu) --------
    const int cr = tid >> 4;                   // 0..31
    const int cu = tid & 15;                   // 0..15
    const int grow = grp * 32 + cr;            // global batch row
    const int j  = ng * 16 + cu;               // global hidden unit
    const float bi  = bias[layer * 4096 + j];
    const float bfv = bias[layer * 4096 + 1024 + j];
    const float bg  = bias[layer * 4096 + 2048 + j];
    const float bo  = bias[layer * 4096 + 3072 + j];
    float c_reg = 0.f;                         // cell state, 512 steps

    unsigned* myflag = flags + layer * 128 + grp * 64 + ng;
    // per-wave poll target: x-waves need L0 flags (out0); h-waves need own
    // layer's flags (out0 for L0, hping for L1).
    const int cls = xw ? 0 : layer;
    const unsigned* fpoll = flags + cls * 128 + grp * 64 + lane;

    for (int u = 0; u <= SEQL; ++u) {
        const int t = layer ? (u - 1) : u;
        const bool active = layer ? (u >= 1) : (u < SEQL);

        if (active) {
            // ---------------- A acquisition ------------------------------
            short8 a[2][8];
            if (!layer && xw) {
                // L0 x-half: static xbf, row-major, plain cached. No poll.
                const __hip_bfloat16* ab =
                    xbf + (size_t)t * STEP_ELEMS + (size_t)rb * 1024 + kb;
                #pragma unroll
                for (int mt = 0; mt < 2; ++mt)
                    #pragma unroll
                    for (int kkl = 0; kkl < 8; ++kkl)
                        a[mt][kkl] =
                            *(const short8*)(ab + mt * 16384 + kkl * 32);
            } else if (!xw && t == 0) {
                // h(-1) = 0: zero A registers, skip load & poll entirely.
                #pragma unroll
                for (int mt = 0; mt < 2; ++mt)
                    #pragma unroll
                    for (int kkl = 0; kkl < 8; ++kkl)
                        a[mt][kkl] = (short8){0, 0, 0, 0, 0, 0, 0, 0};
            } else {
                // per-wave dependency poll: all 64 producer flags >= u
                {
                    const unsigned need = (unsigned)u;
                    for (;;) {
                        unsigned v = ld_coh_u32(fpoll);
                        if (__all((int)(v >= need))) break;
                        __builtin_amdgcn_s_sleep(1);
                    }
                }
                // plane-layout fragment loads (8 consecutive units @ row)
                if (xw) {
                    // L1 x-half: out0[t], fresh address -> L2-cacheable
                    const __hip_bfloat16* sl = out0 + (size_t)t * STEP_ELEMS;
                    #pragma unroll
                    for (int mt = 0; mt < 2; ++mt)
                        #pragma unroll
                        for (int kkl = 0; kkl < 8; ++kkl) {
                            int k0 = kb + kkl * 32;
                            a[mt][kkl] = ld16_l2(sl + ((k0 >> 4) << 10) +
                                                 (rb + mt * 16) * 16 +
                                                 (k0 & 8));
                        }
                } else if (!layer) {
                    // L0 h-half: out0[t-1], fresh address -> L2-cacheable
                    const __hip_bfloat16* sl =
                        out0 + (size_t)(t - 1) * STEP_ELEMS;
                    #pragma unroll
                    for (int mt = 0; mt < 2; ++mt)
                        #pragma unroll
                        for (int kkl = 0; kkl < 8; ++kkl) {
                            int k0 = kb + kkl * 32;
                            a[mt][kkl] = ld16_l2(sl + ((k0 >> 4) << 10) +
                                                 (rb + mt * 16) * 16 +
                                                 (k0 & 8));
                        }
                } else {
                    // L1 h-half: hping (reused address) -> MALL coherent
                    const __hip_bfloat16* sl =
                        hping + (size_t)((t - 1) & 1) * STEP_ELEMS;
                    #pragma unroll
                    for (int mt = 0; mt < 2; ++mt)
                        #pragma unroll
                        for (int kkl = 0; kkl < 8; ++kkl) {
                            int k0 = kb + kkl * 32;
                            a[mt][kkl] = ld16_coh(sl + ((k0 >> 4) << 10) +
                                                  (rb + mt * 16) * 16 +
                                                  (k0 & 8));
                        }
                }
                asm volatile("s_waitcnt vmcnt(0)" ::: "memory");
                __builtin_amdgcn_sched_barrier(0);
            }

            // ---------------- 64 register-only MFMAs ---------------------
            floatx4 acc[2][4];
            #pragma unroll
            for (int mt = 0; mt < 2; ++mt)
                #pragma unroll
                for (int nt = 0; nt < 4; ++nt)
                    acc[mt][nt] = (floatx4){0.f, 0.f, 0.f, 0.f};
            #pragma unroll
            for (int kkl = 0; kkl < 8; ++kkl)
                #pragma unroll
                for (int mt = 0; mt < 2; ++mt)
                    #pragma unroll
                    for (int nt = 0; nt < 4; ++nt)
                        acc[mt][nt] = __builtin_amdgcn_mfma_f32_16x16x32_bf16(
                            a[mt][kkl], wf[nt][kkl], acc[mt][nt], 0, 0, 0);

            // ---------------- K-partials to LDS (transposed) -------------
            {
                const int col = lane & 15;
                const int rq  = (lane >> 4) * 4;
                #pragma unroll
                for (int mt = 0; mt < 2; ++mt)
                    #pragma unroll
                    for (int nt = 0; nt < 4; ++nt) {
                        float* base = &Glds[w][nt * 16 + col][mt * 16 + rq];
                        *(float2*)(base)     = (float2){acc[mt][nt][0],
                                                        acc[mt][nt][1]};
                        *(float2*)(base + 2) = (float2){acc[mt][nt][2],
                                                        acc[mt][nt][3]};
                    }
            }
        }
        __syncthreads();                       // sync1: Glds ready

        float hn = 0.f, cn = 0.f;
        if (active) {
            // ---------------- 8-way reduce + fused LSTM cell -------------
            float v0 = 0.f, v1 = 0.f, v2 = 0.f, v3 = 0.f;
            #pragma unroll
            for (int ww = 0; ww < 8; ++ww) {
                v0 += Glds[ww][cu][cr];
                v1 += Glds[ww][16 + cu][cr];
                v2 += Glds[ww][32 + cu][cr];
                v3 += Glds[ww][48 + cu][cr];
            }
            float iv = 1.f / (1.f + __expf(-(v0 + bi)));
            float fv = 1.f / (1.f + __expf(-(v1 + bfv)));
            float gv = tanhf(v2 + bg);
            float ov = 1.f / (1.f + __expf(-(v3 + bo)));
            cn = fv * c_reg + iv * gv;
            hn = ov * tanhf(cn);
            c_reg = cn;

            // ---------------- h publish: plane layout, write-through -----
            __hip_bfloat16 hb = __float2bfloat16(hn);
            unsigned hu = *(const unsigned short*)&hb;
            unsigned other = (unsigned)__shfl_xor((int)hu, 1);
            if (!(cu & 1)) {
                unsigned pack = hu | (other << 16);
                __hip_bfloat16* hout =
                    layer ? (hping + (size_t)(t & 1) * STEP_ELEMS)
                          : (out0 + (size_t)t * STEP_ELEMS);
                st_coh_u32((unsigned*)(hout + ng * 1024 + grow * 16 + cu),
                           pack);
            }
        }
        asm volatile("s_waitcnt vmcnt(0)" ::: "memory");  // drain h-stores
        __syncthreads();                       // sync2: all waves drained
        if (u < SEQL && tid == 0)
            st_coh_u32(myflag, (unsigned)(u + 1));

        // ---------------- deferred off-path outputs ----------------------
        if (active) {
            if (layer)
                __builtin_nontemporal_store(
                    hn, out1 + (size_t)t * STEP_ELEMS + grow * 1024 + j);
            if (t == SEQL - 1) {
                __builtin_nontemporal_store(
                    hn, hf + (size_t)layer * STEP_ELEMS + grow * 1024 + j);
                __builtin_nontemporal_store(
                    cn, cfin + (size_t)layer * STEP_ELEMS + grow * 1024 + j);
            }
        }
    }
}

// ---------------------------------------------------------------------------
extern "C" void kernel_launch(void* const* d_in, const int* in_sizes, int n_in,
                              void* d_out, int out_size, void* d_ws, size_t ws_size,
                              hipStream_t stream)
{
    const float* x    = (const float*)d_in[0];
    const float* U0   = (const float*)d_in[1];
    const float* V0   = (const float*)d_in[2];
    const float* bih0 = (const float*)d_in[3];
    const float* bhh0 = (const float*)d_in[4];
    const float* U1   = (const float*)d_in[5];
    const float* V1   = (const float*)d_in[6];
    const float* bih1 = (const float*)d_in[7];
    const float* bhh1 = (const float*)d_in[8];

    char* ws = (char*)d_ws;
    short8*         Wf    = (short8*)(ws + OFF_WFRAG);
    __hip_bfloat16* xbf   = (__hip_bfloat16*)(ws + OFF_XBF);
    __hip_bfloat16* out0  = (__hip_bfloat16*)(ws + OFF_OUT0);
    __hip_bfloat16* hping = (__hip_bfloat16*)(ws + OFF_HPING);
    float*          bias  = (float*)(ws + OFF_BIAS);
    unsigned*       flg   = (unsigned*)(ws + OFF_FLAGS);

    prep_misc<<<dim3(33), dim3(256), 0, stream>>>(bih0, bhh0, bih1, bhh1,
                                                  bias, flg);
    prep_x<<<dim3(32768), dim3(256), 0, stream>>>(x, xbf);
    prep_w<<<dim3(8192), dim3(256), 0, stream>>>(U0, V0, U1, V1, Wf);

    float* out1 = (float*)d_out;               // [512][64][1024]
    float* hfp  = out1 + 33554432;             // [2][64][1024]
    float* cfp  = hfp + 131072;                // [2][64][1024]

    void* kargs[] = { (void*)&xbf, (void*)&out0, (void*)&Wf, (void*)&bias,
                      (void*)&hping, (void*)&out1, (void*)&hfp, (void*)&cfp,
                      (void*)&flg };
    hipLaunchCooperativeKernel((void*)lstm_persist, dim3(256), dim3(512),
                               kargs, 0, stream);
}